// Round 2
// baseline (6240.240 us; speedup 1.0000x reference)
//
#include <hip/hip_runtime.h>
#include <math.h>

#define T_SEQ 8192
#define D_MODEL 1024
#define DK 64
#define DKP 128
#define DV 64
#define NCAT 385   // 64 q | 64 k | 64 v | 128 alpha1 | 1 beta | 64 out_gate
#define RMS_EPS 1.1920929e-07f

__device__ __forceinline__ float wave_sum(float x) {
#pragma unroll
  for (int off = 1; off < 64; off <<= 1) x += __shfl_xor(x, off, 64);
  return x;
}

__device__ __forceinline__ float sigmoidf_(float x) { return 1.0f / (1.0f + expf(-x)); }
__device__ __forceinline__ float siluf_(float x) { return x / (1.0f + expf(-x)); }

// ---------------- tables: f32 freq and f32 k-phase shift (match numpy f32 semantics) ------
__global__ void init_tables(const float* __restrict__ delta, float* __restrict__ freq,
                            float* __restrict__ shift) {
  int i = threadIdx.x;  // 64
  // numpy: 10000.0 ** (arange(64,f32)/64) via correctly-rounded powf == f64 pow -> f32
  freq[i] = (float)pow(10000.0, (double)i / 64.0);
  // numpy: fl32(-2*pi) * fl32(sigmoid(delta))  (all f32 ops)
  float s = 1.0f / (1.0f + expf(-delta[i]));
  shift[i] = -6.2831855f * s;  // f32(-2*pi) * s, rounded f32
}

// ---------------- concat weights for fused projection GEMM ----------------
__global__ void build_wcat(const float* __restrict__ Wq, const float* __restrict__ Wk,
                           const float* __restrict__ Wv, const float* __restrict__ Wa1,
                           const float* __restrict__ Wb, const float* __restrict__ Wg,
                           float* __restrict__ Wcat) {
  int idx = blockIdx.x * 256 + threadIdx.x;
  if (idx >= NCAT * D_MODEL) return;
  int row = idx >> 10, col = idx & 1023;
  float v;
  if (row < 64) v = Wq[row * D_MODEL + col];
  else if (row < 128) v = Wk[(row - 64) * D_MODEL + col];
  else if (row < 192) v = Wv[(row - 128) * D_MODEL + col];
  else if (row < 320) v = Wa1[(row - 192) * D_MODEL + col];
  else if (row == 320) v = Wb[col];
  else v = Wg[(row - 321) * D_MODEL + col];
  Wcat[idx] = v;
}

// ---------------- generic f32 GEMM: C = act(A @ B^T + add) ----------------
// A: M x K row-major, B: N x K row-major, C/add: M x N. act: 0 none, 1 sigmoid, 2 silu
__global__ __launch_bounds__(256) void gemm_f32(const float* __restrict__ A,
                                                const float* __restrict__ B,
                                                const float* __restrict__ add,
                                                float* __restrict__ C,
                                                int M, int N, int K, int act) {
  __shared__ float As[16][68];
  __shared__ float Bs[16][68];
  const int bm = blockIdx.x * 64;
  const int bn = blockIdx.y * 64;
  const int tid = threadIdx.x;
  const int tm = tid >> 4, tn = tid & 15;
  const int lk = (tid & 3) << 2, lm = tid >> 2;
  float acc[4][4] = {{0.f}};
  const int ar = bm + lm;
  const int br = bn + lm;
  for (int k0 = 0; k0 < K; k0 += 16) {
    float4 a4 = make_float4(0.f, 0.f, 0.f, 0.f);
    float4 b4 = make_float4(0.f, 0.f, 0.f, 0.f);
    if (ar < M) a4 = *(const float4*)(A + (size_t)ar * K + k0 + lk);
    if (br < N) b4 = *(const float4*)(B + (size_t)br * K + k0 + lk);
    __syncthreads();
    As[lk][lm] = a4.x; As[lk + 1][lm] = a4.y; As[lk + 2][lm] = a4.z; As[lk + 3][lm] = a4.w;
    Bs[lk][lm] = b4.x; Bs[lk + 1][lm] = b4.y; Bs[lk + 2][lm] = b4.z; Bs[lk + 3][lm] = b4.w;
    __syncthreads();
#pragma unroll
    for (int kk = 0; kk < 16; ++kk) {
      float4 av = *(const float4*)&As[kk][tm << 2];
      float4 bv = *(const float4*)&Bs[kk][tn << 2];
      float a_[4] = {av.x, av.y, av.z, av.w};
      float b_[4] = {bv.x, bv.y, bv.z, bv.w};
#pragma unroll
      for (int i = 0; i < 4; ++i)
#pragma unroll
        for (int j = 0; j < 4; ++j) acc[i][j] = fmaf(a_[i], b_[j], acc[i][j]);
    }
  }
#pragma unroll
  for (int i = 0; i < 4; ++i) {
    int row = bm + (tm << 2) + i;
    if (row >= M) continue;
#pragma unroll
    for (int j = 0; j < 4; ++j) {
      int col = bn + (tn << 2) + j;
      if (col >= N) continue;
      float r = acc[i][j];
      if (add) r += add[(size_t)row * N + col];
      if (act == 1) r = 1.0f / (1.0f + expf(-r));
      else if (act == 2) r = r / (1.0f + expf(-r));
      C[(size_t)row * N + col] = r;
    }
  }
}

// ---------------- activations: v=silu, a1=silu, beta=sigmoid ----------------
__global__ void act_split(const float* __restrict__ C1, float* __restrict__ vb,
                          float* __restrict__ a1s, float* __restrict__ betab) {
  int idx = blockIdx.x * 256 + threadIdx.x;
  if (idx >= T_SEQ * 193) return;
  int t = idx / 193, j = idx % 193;
  if (j < 64) {
    float x = C1[(size_t)t * NCAT + 128 + j];
    vb[(size_t)t * DV + j] = siluf_(x);
  } else if (j < 192) {
    float x = C1[(size_t)t * NCAT + 192 + (j - 64)];
    a1s[(size_t)t * DKP + (j - 64)] = siluf_(x);
  } else {
    betab[t] = sigmoidf_(C1[(size_t)t * NCAT + 320]);
  }
}

// ---------------- PoPE: f32 phase arithmetic (matches numpy), accurate trig ----------------
__global__ __launch_bounds__(256) void pope_kernel(const float* __restrict__ C1,
                                                   const float* __restrict__ freq,
                                                   const float* __restrict__ shift,
                                                   float* __restrict__ qb, float* __restrict__ kb) {
  int idx = blockIdx.x * 256 + threadIdx.x;
  if (idx >= T_SEQ * DK) return;
  int t = idx >> 6;
  int i = idx & 63;
  const double TWO_PI = 6.283185307179586476925286766559;
  const double INV_TWO_PI = 0.15915494309189533576888376337251;
  // f32 phase values, bit-matching numpy's f32 ops
  float phiq = (float)t * freq[i];          // f32 multiply
  float phik = phiq + shift[i];             // f32 add
  // q
  float xq = C1[(size_t)t * NCAT + i];
  float muq = xq > 15.f ? xq : log1pf(expf(xq));
  double w = (double)phiq * INV_TWO_PI;
  w -= floor(w);
  float aq = (float)(w * TWO_PI);
  qb[(size_t)t * DKP + i] = muq * cosf(aq);
  qb[(size_t)t * DKP + 64 + i] = muq * sinf(aq);
  // k
  float xk = C1[(size_t)t * NCAT + DK + i];
  float muk = xk > 15.f ? xk : log1pf(expf(xk));
  double wk = (double)phik * INV_TWO_PI;
  wk -= floor(wk);
  float ak = (float)(wk * TWO_PI);
  kb[(size_t)t * DKP + i] = muk * cosf(ak);
  kb[(size_t)t * DKP + 64 + i] = muk * sinf(ak);
}

// ---------------- sequential scan: one block (1 wave) per output column ----------------
// S_t = Diag(a) S_{t-1} + b k (v - k^T Diag(a) S_{t-1});  o_t = S_t^T q_t
// lane l holds state rows 2l, 2l+1 of column c = blockIdx.x
__global__ __launch_bounds__(64) void scan_kernel(const float* __restrict__ qb,
                                                  const float* __restrict__ kb,
                                                  const float* __restrict__ alphab,
                                                  const float* __restrict__ vb,
                                                  const float* __restrict__ betab,
                                                  float* __restrict__ ob) {
  const int c = blockIdx.x;
  const int l = threadIdx.x;
  const float2* k2 = (const float2*)kb;
  const float2* a2 = (const float2*)alphab;
  const float2* q2 = (const float2*)qb;
  float s0 = 0.f, s1 = 0.f;
  float2 kv = k2[l], av = a2[l], qv = q2[l];
  float vt = vb[c], bt = betab[0];
  for (int t = 0; t < T_SEQ; ++t) {
    // prefetch next step's inputs (hide L2 latency under the shuffle chain)
    int tn = (t + 1 < T_SEQ) ? t + 1 : T_SEQ - 1;
    float2 kn = k2[tn * 64 + l];
    float2 an = a2[tn * 64 + l];
    float2 qn = q2[tn * 64 + l];
    float vn = vb[tn * DV + c];
    float bn = betab[tn];
    // step
    s0 *= av.x; s1 *= av.y;
    float dot = wave_sum(kv.x * s0 + kv.y * s1);
    float cf = bt * (vt - dot);
    s0 = fmaf(cf, kv.x, s0);
    s1 = fmaf(cf, kv.y, s1);
    float osum = wave_sum(qv.x * s0 + qv.y * s1);
    if (l == 0) ob[(size_t)t * DV + c] = osum;
    kv = kn; av = an; qv = qn; vt = vn; bt = bn;
  }
}

// ---------------- post: og = rmsnorm(o)*pnw*sigmoid(gate_pre) ----------------
__global__ __launch_bounds__(256) void post_kernel(const float* __restrict__ ob,
                                                   const float* __restrict__ C1,
                                                   const float* __restrict__ pnw,
                                                   float* __restrict__ og) {
  int row = blockIdx.x * 4 + (threadIdx.x >> 6);
  int c = threadIdx.x & 63;
  float o = ob[(size_t)row * DV + c];
  float ss = wave_sum(o * o);
  float scale = 1.0f / sqrtf(ss * (1.0f / DV) + RMS_EPS);
  float g = sigmoidf_(C1[(size_t)row * NCAT + 321 + c]);
  og[(size_t)row * DV + c] = o * scale * pnw[c] * g;
}

// ---------------- rmsnorm over d=1024 rows ----------------
__global__ __launch_bounds__(256) void rmsnorm_rows(const float* __restrict__ x,
                                                    const float* __restrict__ w,
                                                    float* __restrict__ y) {
  int row = blockIdx.x;
  const float4* x4 = (const float4*)(x + (size_t)row * D_MODEL);
  const float4* w4 = (const float4*)w;
  float4 v = x4[threadIdx.x];
  float ss = v.x * v.x + v.y * v.y + v.z * v.z + v.w * v.w;
  ss = wave_sum(ss);
  __shared__ float red[4];
  if ((threadIdx.x & 63) == 0) red[threadIdx.x >> 6] = ss;
  __syncthreads();
  float tot = red[0] + red[1] + red[2] + red[3];
  float scale = 1.0f / sqrtf(tot * (1.0f / D_MODEL) + RMS_EPS);
  float4 wv = w4[threadIdx.x];
  float4 o;
  o.x = v.x * scale * wv.x; o.y = v.y * scale * wv.y;
  o.z = v.z * scale * wv.z; o.w = v.w * scale * wv.w;
  ((float4*)(y + (size_t)row * D_MODEL))[threadIdx.x] = o;
}

// ---------------- G *= U (silu already applied to G in its GEMM epilogue) ----------------
__global__ void combine_kernel(float* __restrict__ G, const float* __restrict__ U, int n4) {
  int i = blockIdx.x * 256 + threadIdx.x;
  if (i >= n4) return;
  float4 g = ((float4*)G)[i];
  float4 u = ((const float4*)U)[i];
  g.x *= u.x; g.y *= u.y; g.z *= u.z; g.w *= u.w;
  ((float4*)G)[i] = g;
}

extern "C" void kernel_launch(void* const* d_in, const int* in_sizes, int n_in,
                              void* d_out, int out_size, void* d_ws, size_t ws_size,
                              hipStream_t stream) {
  const float* x_seq = (const float*)d_in[0];
  const float* W_q = (const float*)d_in[1];
  const float* W_k = (const float*)d_in[2];
  const float* W_v = (const float*)d_in[3];
  const float* pope_delta = (const float*)d_in[4];
  const float* W_a1 = (const float*)d_in[5];
  const float* W_a2 = (const float*)d_in[6];
  const float* W_beta = (const float*)d_in[7];
  const float* pnw = (const float*)d_in[8];
  const float* out_gate_W = (const float*)d_in[9];
  const float* W_out = (const float*)d_in[10];
  const float* ffn_norm_w = (const float*)d_in[11];
  const float* Wg = (const float*)d_in[12];
  const float* Wu = (const float*)d_in[13];
  const float* Wd = (const float*)d_in[14];
  float* out = (float*)d_out;

  float* freq_f = (float*)d_ws;
  float* shift_f = freq_f + 64;
  float* F = (float*)((char*)d_ws + 1024);
  float* Wcat = F;                  // 385*1024
  float* og = Wcat + 394240;        // 8192*64
  float* BIG = og + 524288;
  // phase 1 (lives in BIG)
  float* C1 = BIG;                  // 8192*385
  float* qb = C1 + 3153920;         // 8192*128
  float* kb = qb + 1048576;
  float* alphab = kb + 1048576;
  float* a1s = alphab + 1048576;
  float* vb = a1s + 1048576;        // 8192*64
  float* betab = vb + 524288;       // 8192
  float* ob = betab + 8192;         // 8192*64
  // phase 2 (reuses BIG; phase-1 buffers dead by then)
  float* hb = BIG;                  // 8192*1024
  float* Gb = hb + 8388608;
  float* Ub = Gb + 8388608;

  (void)in_sizes; (void)n_in; (void)out_size; (void)ws_size;

  init_tables<<<1, 64, 0, stream>>>(pope_delta, freq_f, shift_f);
  build_wcat<<<(NCAT * D_MODEL + 255) / 256, 256, 0, stream>>>(W_q, W_k, W_v, W_a1, W_beta,
                                                               out_gate_W, Wcat);
  // fused projection GEMM: C1 = x @ Wcat^T  (8192 x 385, K=1024)
  gemm_f32<<<dim3(128, 7), 256, 0, stream>>>(x_seq, Wcat, nullptr, C1, T_SEQ, NCAT, D_MODEL, 0);
  act_split<<<(T_SEQ * 193 + 255) / 256, 256, 0, stream>>>(C1, vb, a1s, betab);
  // alpha = sigmoid(silu(a1) @ W_a2^T)  (8192 x 128, K=128)
  gemm_f32<<<dim3(128, 2), 256, 0, stream>>>(a1s, W_a2, nullptr, alphab, T_SEQ, DKP, DKP, 1);
  pope_kernel<<<(T_SEQ * DK + 255) / 256, 256, 0, stream>>>(C1, freq_f, shift_f, qb, kb);
  scan_kernel<<<64, 64, 0, stream>>>(qb, kb, alphab, vb, betab, ob);
  post_kernel<<<T_SEQ / 4, 256, 0, stream>>>(ob, C1, pnw, og);
  // xres = x_seq + og @ W_out^T  (8192 x 1024, K=64) -> lives in d_out
  gemm_f32<<<dim3(128, 16), 256, 0, stream>>>(og, W_out, x_seq, out, T_SEQ, D_MODEL, DV, 0);
  rmsnorm_rows<<<T_SEQ, 256, 0, stream>>>(out, ffn_norm_w, hb);
  // FFN
  gemm_f32<<<dim3(128, 16), 256, 0, stream>>>(hb, Wg, nullptr, Gb, T_SEQ, D_MODEL, D_MODEL, 2);
  gemm_f32<<<dim3(128, 16), 256, 0, stream>>>(hb, Wu, nullptr, Ub, T_SEQ, D_MODEL, D_MODEL, 0);
  combine_kernel<<<(T_SEQ * D_MODEL / 4 + 255) / 256, 256, 0, stream>>>(Gb, Ub,
                                                                        T_SEQ * D_MODEL / 4);
  // out = xres + (silu(G)*U) @ Wd^T
  gemm_f32<<<dim3(128, 16), 256, 0, stream>>>(Gb, Wd, out, out, T_SEQ, D_MODEL, D_MODEL, 0);
}

// Round 3
// 1564.406 us; speedup vs baseline: 3.9889x; 3.9889x over previous
//
#include <hip/hip_runtime.h>
#include <math.h>

#define T_SEQ 8192
#define D_MODEL 1024
#define DK 64
#define DKP 128
#define DV 64
#define NCAT 385   // 64 q | 64 k | 64 v | 128 alpha1 | 1 beta | 64 out_gate
#define RMS_EPS 1.1920929e-07f
#define CHUNK 128
#define NCHUNK 64  // T_SEQ / CHUNK

__device__ __forceinline__ float wave_sum(float x) {
#pragma unroll
  for (int off = 1; off < 64; off <<= 1) x += __shfl_xor(x, off, 64);
  return x;
}

__device__ __forceinline__ float sigmoidf_(float x) { return 1.0f / (1.0f + expf(-x)); }
__device__ __forceinline__ float siluf_(float x) { return x / (1.0f + expf(-x)); }

// ---------------- tables: f32 freq and f32 k-phase shift (match numpy f32 semantics) ------
__global__ void init_tables(const float* __restrict__ delta, float* __restrict__ freq,
                            float* __restrict__ shift) {
  int i = threadIdx.x;  // 64
  freq[i] = (float)pow(10000.0, (double)i / 64.0);
  float s = 1.0f / (1.0f + expf(-delta[i]));
  shift[i] = -6.2831855f * s;
}

// ---------------- concat weights for fused projection GEMM ----------------
__global__ void build_wcat(const float* __restrict__ Wq, const float* __restrict__ Wk,
                           const float* __restrict__ Wv, const float* __restrict__ Wa1,
                           const float* __restrict__ Wb, const float* __restrict__ Wg,
                           float* __restrict__ Wcat) {
  int idx = blockIdx.x * 256 + threadIdx.x;
  if (idx >= NCAT * D_MODEL) return;
  int row = idx >> 10, col = idx & 1023;
  float v;
  if (row < 64) v = Wq[row * D_MODEL + col];
  else if (row < 128) v = Wk[(row - 64) * D_MODEL + col];
  else if (row < 192) v = Wv[(row - 128) * D_MODEL + col];
  else if (row < 320) v = Wa1[(row - 192) * D_MODEL + col];
  else if (row == 320) v = Wb[col];
  else v = Wg[(row - 321) * D_MODEL + col];
  Wcat[idx] = v;
}

// ---------------- generic f32 GEMM: C = act(A @ B^T + add) ----------------
__global__ __launch_bounds__(256) void gemm_f32(const float* __restrict__ A,
                                                const float* __restrict__ B,
                                                const float* __restrict__ add,
                                                float* __restrict__ C,
                                                int M, int N, int K, int act) {
  __shared__ float As[16][68];
  __shared__ float Bs[16][68];
  const int bm = blockIdx.x * 64;
  const int bn = blockIdx.y * 64;
  const int tid = threadIdx.x;
  const int tm = tid >> 4, tn = tid & 15;
  const int lk = (tid & 3) << 2, lm = tid >> 2;
  float acc[4][4] = {{0.f}};
  const int ar = bm + lm;
  const int br = bn + lm;
  for (int k0 = 0; k0 < K; k0 += 16) {
    float4 a4 = make_float4(0.f, 0.f, 0.f, 0.f);
    float4 b4 = make_float4(0.f, 0.f, 0.f, 0.f);
    if (ar < M) a4 = *(const float4*)(A + (size_t)ar * K + k0 + lk);
    if (br < N) b4 = *(const float4*)(B + (size_t)br * K + k0 + lk);
    __syncthreads();
    As[lk][lm] = a4.x; As[lk + 1][lm] = a4.y; As[lk + 2][lm] = a4.z; As[lk + 3][lm] = a4.w;
    Bs[lk][lm] = b4.x; Bs[lk + 1][lm] = b4.y; Bs[lk + 2][lm] = b4.z; Bs[lk + 3][lm] = b4.w;
    __syncthreads();
#pragma unroll
    for (int kk = 0; kk < 16; ++kk) {
      float4 av = *(const float4*)&As[kk][tm << 2];
      float4 bv = *(const float4*)&Bs[kk][tn << 2];
      float a_[4] = {av.x, av.y, av.z, av.w};
      float b_[4] = {bv.x, bv.y, bv.z, bv.w};
#pragma unroll
      for (int i = 0; i < 4; ++i)
#pragma unroll
        for (int j = 0; j < 4; ++j) acc[i][j] = fmaf(a_[i], b_[j], acc[i][j]);
    }
  }
#pragma unroll
  for (int i = 0; i < 4; ++i) {
    int row = bm + (tm << 2) + i;
    if (row >= M) continue;
#pragma unroll
    for (int j = 0; j < 4; ++j) {
      int col = bn + (tn << 2) + j;
      if (col >= N) continue;
      float r = acc[i][j];
      if (add) r += add[(size_t)row * N + col];
      if (act == 1) r = 1.0f / (1.0f + expf(-r));
      else if (act == 2) r = r / (1.0f + expf(-r));
      C[(size_t)row * N + col] = r;
    }
  }
}

// ---------------- activations: v=silu, a1=silu, beta=sigmoid ----------------
__global__ void act_split(const float* __restrict__ C1, float* __restrict__ vb,
                          float* __restrict__ a1s, float* __restrict__ betab) {
  int idx = blockIdx.x * 256 + threadIdx.x;
  if (idx >= T_SEQ * 193) return;
  int t = idx / 193, j = idx % 193;
  if (j < 64) {
    float x = C1[(size_t)t * NCAT + 128 + j];
    vb[(size_t)t * DV + j] = siluf_(x);
  } else if (j < 192) {
    float x = C1[(size_t)t * NCAT + 192 + (j - 64)];
    a1s[(size_t)t * DKP + (j - 64)] = siluf_(x);
  } else {
    betab[t] = sigmoidf_(C1[(size_t)t * NCAT + 320]);
  }
}

// ---------------- PoPE: f32 phase arithmetic (matches numpy), accurate trig ----------------
__global__ __launch_bounds__(256) void pope_kernel(const float* __restrict__ C1,
                                                   const float* __restrict__ freq,
                                                   const float* __restrict__ shift,
                                                   float* __restrict__ qb, float* __restrict__ kb) {
  int idx = blockIdx.x * 256 + threadIdx.x;
  if (idx >= T_SEQ * DK) return;
  int t = idx >> 6;
  int i = idx & 63;
  const double TWO_PI = 6.283185307179586476925286766559;
  const double INV_TWO_PI = 0.15915494309189533576888376337251;
  float phiq = (float)t * freq[i];          // f32 multiply (matches numpy)
  float phik = phiq + shift[i];             // f32 add (matches numpy)
  float xq = C1[(size_t)t * NCAT + i];
  float muq = xq > 15.f ? xq : log1pf(expf(xq));
  double w = (double)phiq * INV_TWO_PI;
  w -= floor(w);
  float aq = (float)(w * TWO_PI);
  qb[(size_t)t * DKP + i] = muq * cosf(aq);
  qb[(size_t)t * DKP + 64 + i] = muq * sinf(aq);
  float xk = C1[(size_t)t * NCAT + DK + i];
  float muk = xk > 15.f ? xk : log1pf(expf(xk));
  double wk = (double)phik * INV_TWO_PI;
  wk -= floor(wk);
  float ak = (float)(wk * TWO_PI);
  kb[(size_t)t * DKP + i] = muk * cosf(ak);
  kb[(size_t)t * DKP + 64 + i] = muk * sinf(ak);
}

// ================= chunked scan =================
// Recurrence per column: s <- a (.) s;  dot = k . s;  s <- s + b*(v - dot)*k
// M_t = (I - b k k^T) Diag(a) is shared across columns; every column of any matrix
// propagated by M_t follows the same scalar recurrence (v-drive = 0 for basis columns).

// Pass A: per (chunk, column cc): cc<128 -> basis column e_cc (chunk transition),
//         cc>=128 -> driven column c=cc-128 with zero init (local state).
// Writes PT[chunk][col][row] (P transposed, coalesced) and fstate[chunk][row][col].
__global__ __launch_bounds__(64) void scan_passA(const float* __restrict__ kb,
                                                 const float* __restrict__ alphab,
                                                 const float* __restrict__ vb,
                                                 const float* __restrict__ betab,
                                                 float* __restrict__ PT,
                                                 float* __restrict__ fstate) {
  const int chunk = blockIdx.x;
  const int cc = blockIdx.y;  // 0..191
  const int l = threadIdx.x;
  const bool isP = cc < 128;
  const int c = isP ? 0 : (cc - 128);
  const float2* k2 = (const float2*)kb + (size_t)chunk * CHUNK * 64;
  const float2* a2 = (const float2*)alphab + (size_t)chunk * CHUNK * 64;
  const float* vcol = vb + (size_t)chunk * CHUNK * 64 + c;
  const float* bp = betab + (size_t)chunk * CHUNK;
  float s0, s1;
  if (isP) {
    s0 = (2 * l == cc) ? 1.f : 0.f;
    s1 = (2 * l + 1 == cc) ? 1.f : 0.f;
  } else {
    s0 = 0.f; s1 = 0.f;
  }
  float2 kv = k2[l], av = a2[l];
  float vt = isP ? 0.f : vcol[0];
  float bt = bp[0];
  for (int t = 0; t < CHUNK; ++t) {
    int tn = (t + 1 < CHUNK) ? t + 1 : CHUNK - 1;
    float2 kn = k2[(size_t)tn * 64 + l];
    float2 an = a2[(size_t)tn * 64 + l];
    float vn = isP ? 0.f : vcol[(size_t)tn * 64];
    float bn = bp[tn];
    s0 *= av.x; s1 *= av.y;
    float dot = wave_sum(kv.x * s0 + kv.y * s1);
    float cf = bt * (vt - dot);
    s0 = fmaf(cf, kv.x, s0);
    s1 = fmaf(cf, kv.y, s1);
    kv = kn; av = an; vt = vn; bt = bn;
  }
  if (isP) {
    float2* dst = (float2*)(PT + (size_t)chunk * 16384 + (size_t)cc * 128);
    dst[l] = make_float2(s0, s1);
  } else {
    fstate[(size_t)chunk * 8192 + (size_t)(2 * l) * 64 + c] = s0;
    fstate[(size_t)chunk * 8192 + (size_t)(2 * l + 1) * 64 + c] = s1;
  }
}

// Combine: per column c, sequentially s_in(j+1) = P_j s_in(j) + f_j. Thread = row.
__global__ __launch_bounds__(128) void scan_combine(const float* __restrict__ PT,
                                                    const float* __restrict__ fstate,
                                                    float* __restrict__ sinbuf) {
  const int c = blockIdx.x;   // 0..63
  const int r = threadIdx.x;  // 0..127
  __shared__ float sv[128];
  float s = 0.f;
  for (int j = 0; j < NCHUNK; ++j) {
    sinbuf[(size_t)j * 8192 + (size_t)r * 64 + c] = s;
    sv[r] = s;
    __syncthreads();
    float acc = fstate[(size_t)j * 8192 + (size_t)r * 64 + c];
    const float* Pj = PT + (size_t)j * 16384;
#pragma unroll 8
    for (int jj = 0; jj < 128; ++jj) acc = fmaf(Pj[(size_t)jj * 128 + r], sv[jj], acc);
    __syncthreads();
    s = acc;
  }
}

// Pass B: exact per-column scan per chunk with true incoming state; emits outputs.
__global__ __launch_bounds__(64) void scan_passB(const float* __restrict__ qb,
                                                 const float* __restrict__ kb,
                                                 const float* __restrict__ alphab,
                                                 const float* __restrict__ vb,
                                                 const float* __restrict__ betab,
                                                 const float* __restrict__ sinbuf,
                                                 float* __restrict__ ob) {
  const int chunk = blockIdx.x;
  const int c = blockIdx.y;  // 0..63
  const int l = threadIdx.x;
  const float2* k2 = (const float2*)kb + (size_t)chunk * CHUNK * 64;
  const float2* a2 = (const float2*)alphab + (size_t)chunk * CHUNK * 64;
  const float2* q2 = (const float2*)qb + (size_t)chunk * CHUNK * 64;
  const float* vcol = vb + (size_t)chunk * CHUNK * 64 + c;
  const float* bp = betab + (size_t)chunk * CHUNK;
  float* ocol = ob + (size_t)chunk * CHUNK * 64 + c;
  float s0 = sinbuf[(size_t)chunk * 8192 + (size_t)(2 * l) * 64 + c];
  float s1 = sinbuf[(size_t)chunk * 8192 + (size_t)(2 * l + 1) * 64 + c];
  float2 kv = k2[l], av = a2[l], qv = q2[l];
  float vt = vcol[0], bt = bp[0];
  for (int t = 0; t < CHUNK; ++t) {
    int tn = (t + 1 < CHUNK) ? t + 1 : CHUNK - 1;
    float2 kn = k2[(size_t)tn * 64 + l];
    float2 an = a2[(size_t)tn * 64 + l];
    float2 qn = q2[(size_t)tn * 64 + l];
    float vn = vcol[(size_t)tn * 64];
    float bn = bp[tn];
    s0 *= av.x; s1 *= av.y;
    float dot = wave_sum(kv.x * s0 + kv.y * s1);
    float cf = bt * (vt - dot);
    s0 = fmaf(cf, kv.x, s0);
    s1 = fmaf(cf, kv.y, s1);
    float osum = wave_sum(qv.x * s0 + qv.y * s1);
    if (l == 0) ocol[(size_t)t * 64] = osum;
    kv = kn; av = an; qv = qn; vt = vn; bt = bn;
  }
}

// ---------------- post: og = rmsnorm(o)*pnw*sigmoid(gate_pre) ----------------
__global__ __launch_bounds__(256) void post_kernel(const float* __restrict__ ob,
                                                   const float* __restrict__ C1,
                                                   const float* __restrict__ pnw,
                                                   float* __restrict__ og) {
  int row = blockIdx.x * 4 + (threadIdx.x >> 6);
  int c = threadIdx.x & 63;
  float o = ob[(size_t)row * DV + c];
  float ss = wave_sum(o * o);
  float scale = 1.0f / sqrtf(ss * (1.0f / DV) + RMS_EPS);
  float g = sigmoidf_(C1[(size_t)row * NCAT + 321 + c]);
  og[(size_t)row * DV + c] = o * scale * pnw[c] * g;
}

// ---------------- rmsnorm over d=1024 rows ----------------
__global__ __launch_bounds__(256) void rmsnorm_rows(const float* __restrict__ x,
                                                    const float* __restrict__ w,
                                                    float* __restrict__ y) {
  int row = blockIdx.x;
  const float4* x4 = (const float4*)(x + (size_t)row * D_MODEL);
  const float4* w4 = (const float4*)w;
  float4 v = x4[threadIdx.x];
  float ss = v.x * v.x + v.y * v.y + v.z * v.z + v.w * v.w;
  ss = wave_sum(ss);
  __shared__ float red[4];
  if ((threadIdx.x & 63) == 0) red[threadIdx.x >> 6] = ss;
  __syncthreads();
  float tot = red[0] + red[1] + red[2] + red[3];
  float scale = 1.0f / sqrtf(tot * (1.0f / D_MODEL) + RMS_EPS);
  float4 wv = w4[threadIdx.x];
  float4 o;
  o.x = v.x * scale * wv.x; o.y = v.y * scale * wv.y;
  o.z = v.z * scale * wv.z; o.w = v.w * scale * wv.w;
  ((float4*)(y + (size_t)row * D_MODEL))[threadIdx.x] = o;
}

// ---------------- G *= U ----------------
__global__ void combine_kernel(float* __restrict__ G, const float* __restrict__ U, int n4) {
  int i = blockIdx.x * 256 + threadIdx.x;
  if (i >= n4) return;
  float4 g = ((float4*)G)[i];
  float4 u = ((const float4*)U)[i];
  g.x *= u.x; g.y *= u.y; g.z *= u.z; g.w *= u.w;
  ((float4*)G)[i] = g;
}

extern "C" void kernel_launch(void* const* d_in, const int* in_sizes, int n_in,
                              void* d_out, int out_size, void* d_ws, size_t ws_size,
                              hipStream_t stream) {
  const float* x_seq = (const float*)d_in[0];
  const float* W_q = (const float*)d_in[1];
  const float* W_k = (const float*)d_in[2];
  const float* W_v = (const float*)d_in[3];
  const float* pope_delta = (const float*)d_in[4];
  const float* W_a1 = (const float*)d_in[5];
  const float* W_a2 = (const float*)d_in[6];
  const float* W_beta = (const float*)d_in[7];
  const float* pnw = (const float*)d_in[8];
  const float* out_gate_W = (const float*)d_in[9];
  const float* W_out = (const float*)d_in[10];
  const float* ffn_norm_w = (const float*)d_in[11];
  const float* Wg = (const float*)d_in[12];
  const float* Wu = (const float*)d_in[13];
  const float* Wd = (const float*)d_in[14];
  float* out = (float*)d_out;

  float* freq_f = (float*)d_ws;
  float* shift_f = freq_f + 64;
  float* F = (float*)((char*)d_ws + 1024);
  float* Wcat = F;                  // 385*1024
  float* og = Wcat + 394240;        // 8192*64
  float* BIG = og + 524288;
  // phase 1 (lives in BIG)
  float* C1 = BIG;                  // 8192*385
  float* qb = C1 + 3153920;         // 8192*128
  float* kb = qb + 1048576;
  float* alphab = kb + 1048576;
  float* a1s = alphab + 1048576;
  float* vb = a1s + 1048576;        // 8192*64
  float* betab = vb + 524288;       // 8192
  float* ob = betab + 8192;         // 8192*64
  float* PT = ob + 524288;          // 64*128*128 = 1,048,576
  float* fstate = PT + 1048576;     // 64*128*64 = 524,288
  float* sinbuf = fstate + 524288;  // 64*128*64 = 524,288
  // phase 2 (reuses BIG; phase-1 buffers dead by then)
  float* hb = BIG;                  // 8192*1024
  float* Gb = hb + 8388608;
  float* Ub = Gb + 8388608;

  (void)in_sizes; (void)n_in; (void)out_size; (void)ws_size;

  init_tables<<<1, 64, 0, stream>>>(pope_delta, freq_f, shift_f);
  build_wcat<<<(NCAT * D_MODEL + 255) / 256, 256, 0, stream>>>(W_q, W_k, W_v, W_a1, W_beta,
                                                               out_gate_W, Wcat);
  gemm_f32<<<dim3(128, 7), 256, 0, stream>>>(x_seq, Wcat, nullptr, C1, T_SEQ, NCAT, D_MODEL, 0);
  act_split<<<(T_SEQ * 193 + 255) / 256, 256, 0, stream>>>(C1, vb, a1s, betab);
  gemm_f32<<<dim3(128, 2), 256, 0, stream>>>(a1s, W_a2, nullptr, alphab, T_SEQ, DKP, DKP, 1);
  pope_kernel<<<(T_SEQ * DK + 255) / 256, 256, 0, stream>>>(C1, freq_f, shift_f, qb, kb);
  // chunked scan
  scan_passA<<<dim3(NCHUNK, 192), 64, 0, stream>>>(kb, alphab, vb, betab, PT, fstate);
  scan_combine<<<64, 128, 0, stream>>>(PT, fstate, sinbuf);
  scan_passB<<<dim3(NCHUNK, 64), 64, 0, stream>>>(qb, kb, alphab, vb, betab, sinbuf, ob);
  post_kernel<<<T_SEQ / 4, 256, 0, stream>>>(ob, C1, pnw, og);
  gemm_f32<<<dim3(128, 16), 256, 0, stream>>>(og, W_out, x_seq, out, T_SEQ, D_MODEL, DV, 0);
  rmsnorm_rows<<<T_SEQ, 256, 0, stream>>>(out, ffn_norm_w, hb);
  gemm_f32<<<dim3(128, 16), 256, 0, stream>>>(hb, Wg, nullptr, Gb, T_SEQ, D_MODEL, D_MODEL, 2);
  gemm_f32<<<dim3(128, 16), 256, 0, stream>>>(hb, Wu, nullptr, Ub, T_SEQ, D_MODEL, D_MODEL, 0);
  combine_kernel<<<(T_SEQ * D_MODEL / 4 + 255) / 256, 256, 0, stream>>>(Gb, Ub,
                                                                        T_SEQ * D_MODEL / 4);
  gemm_f32<<<dim3(128, 16), 256, 0, stream>>>(Gb, Wd, out, out, T_SEQ, D_MODEL, D_MODEL, 0);
}

// Round 4
// 628.188 us; speedup vs baseline: 9.9337x; 2.4903x over previous
//
#include <hip/hip_runtime.h>
#include <math.h>

#define T_SEQ 8192
#define D_MODEL 1024
#define DK 64
#define DKP 128
#define DV 64
#define C1LD 512   // padded fused-projection width (385 -> 512)
#define RMS_EPS 1.1920929e-07f
#define CHUNK 128
#define NCHUNK 64  // T_SEQ / CHUNK

typedef __attribute__((ext_vector_type(8))) __bf16 bf16x8;
typedef __attribute__((ext_vector_type(4))) float f32x4;

__device__ __forceinline__ float wave_sum(float x) {
#pragma unroll
  for (int off = 1; off < 64; off <<= 1) x += __shfl_xor(x, off, 64);
  return x;
}

__device__ __forceinline__ float sigmoidf_(float x) { return 1.0f / (1.0f + expf(-x)); }
__device__ __forceinline__ float siluf_(float x) { return x / (1.0f + expf(-x)); }

__device__ __forceinline__ unsigned short f2bf(float f) {
  unsigned u = __float_as_uint(f);
  u += 0x7fff + ((u >> 16) & 1);  // RNE
  return (unsigned short)(u >> 16);
}

// ---------------- tables: f32 freq and f32 k-phase shift (match numpy f32 semantics) ------
__global__ void init_tables(const float* __restrict__ delta, float* __restrict__ freq,
                            float* __restrict__ shift) {
  int i = threadIdx.x;  // 64
  freq[i] = (float)pow(10000.0, (double)i / 64.0);
  float s = 1.0f / (1.0f + expf(-delta[i]));
  shift[i] = -6.2831855f * s;
}

// ---------------- concat weights (bf16, padded to 512 rows) ----------------
__global__ void build_wcat16(const float* __restrict__ Wq, const float* __restrict__ Wk,
                             const float* __restrict__ Wv, const float* __restrict__ Wa1,
                             const float* __restrict__ Wb, const float* __restrict__ Wg,
                             unsigned short* __restrict__ W16) {
  int idx = blockIdx.x * 256 + threadIdx.x;
  if (idx >= 512 * 1024) return;
  int row = idx >> 10, col = idx & 1023;
  float v = 0.f;
  if (row < 64) v = Wq[row * 1024 + col];
  else if (row < 128) v = Wk[(row - 64) * 1024 + col];
  else if (row < 192) v = Wv[(row - 128) * 1024 + col];
  else if (row < 320) v = Wa1[(row - 192) * 1024 + col];
  else if (row == 320) v = Wb[col];
  else if (row < 385) v = Wg[(row - 321) * 1024 + col];
  W16[idx] = f2bf(v);
}

// ---------------- f32 -> bf16 convert (float4 -> 4x bf16) ----------------
__global__ void conv_bf16(const float* __restrict__ in, unsigned short* __restrict__ out,
                          int n4) {
  int i = blockIdx.x * 256 + threadIdx.x;
  if (i >= n4) return;
  float4 v = ((const float4*)in)[i];
  uint2 o;
  o.x = (unsigned)f2bf(v.x) | ((unsigned)f2bf(v.y) << 16);
  o.y = (unsigned)f2bf(v.z) | ((unsigned)f2bf(v.w) << 16);
  ((uint2*)out)[i] = o;
}

// ---------------- bf16 MFMA GEMM: C(f32) = act(A @ B^T [+ add]) ----------------
// A: M x K bf16 row-major, B: N x K bf16 row-major. M%128==0, N%128==0, K%32==0.
// 128x128 tile, BK=32, 256 threads = 4 waves (2x2 of 64x64). act: 0 none, 2 silu.
__global__ __launch_bounds__(256) void gemm_bf16(const unsigned short* __restrict__ A,
                                                 const unsigned short* __restrict__ B,
                                                 const float* __restrict__ add,
                                                 float* __restrict__ C,
                                                 int M, int N, int K, int act) {
  __shared__ unsigned short As[128 * 40];  // row pad 32 -> 40 ushorts (bank spread)
  __shared__ unsigned short Bs[128 * 40];
  const int tid = threadIdx.x;
  const int tm0 = blockIdx.x * 128, tn0 = blockIdx.y * 128;
  const int lane = tid & 63;
  const int w = tid >> 6;
  const int wr = (w >> 1) * 64, wc = (w & 1) * 64;
  const int fr = lane & 15, fq = lane >> 4;
  f32x4 acc[4][4];
#pragma unroll
  for (int a = 0; a < 4; ++a)
#pragma unroll
    for (int b = 0; b < 4; ++b) acc[a][b] = (f32x4){0.f, 0.f, 0.f, 0.f};

  for (int k0 = 0; k0 < K; k0 += 32) {
    __syncthreads();  // prior compute done before overwrite
#pragma unroll
    for (int j = 0; j < 2; ++j) {
      int idx = tid + 256 * j;           // 0..511
      int row = idx >> 2;                // 0..127
      int kc = (idx & 3) * 8;            // 0,8,16,24
      uint4 va = *(const uint4*)(A + (size_t)(tm0 + row) * K + k0 + kc);
      uint4 vb = *(const uint4*)(B + (size_t)(tn0 + row) * K + k0 + kc);
      *(uint4*)(As + row * 40 + kc) = va;
      *(uint4*)(Bs + row * 40 + kc) = vb;
    }
    __syncthreads();
    bf16x8 af[4], bfr[4];
#pragma unroll
    for (int a = 0; a < 4; ++a)
      af[a] = *(const bf16x8*)(As + (wr + a * 16 + fr) * 40 + fq * 8);
#pragma unroll
    for (int b = 0; b < 4; ++b)
      bfr[b] = *(const bf16x8*)(Bs + (wc + b * 16 + fr) * 40 + fq * 8);
#pragma unroll
    for (int a = 0; a < 4; ++a)
#pragma unroll
      for (int b = 0; b < 4; ++b)
        acc[a][b] = __builtin_amdgcn_mfma_f32_16x16x32_bf16(af[a], bfr[b], acc[a][b], 0, 0, 0);
  }
  // epilogue: D row = tm0+wr+a*16+fq*4+r, col = tn0+wc+b*16+fr
#pragma unroll
  for (int a = 0; a < 4; ++a) {
#pragma unroll
    for (int b = 0; b < 4; ++b) {
#pragma unroll
      for (int r = 0; r < 4; ++r) {
        int row = tm0 + wr + a * 16 + fq * 4 + r;
        int col = tn0 + wc + b * 16 + fr;
        float v = acc[a][b][r];
        if (add) v += add[(size_t)row * N + col];
        if (act == 2) v = v / (1.0f + expf(-v));
        C[(size_t)row * N + col] = v;
      }
    }
  }
}

// ---------------- generic f32 GEMM (kept for the small alpha2 GEMM) ----------------
__global__ __launch_bounds__(256) void gemm_f32(const float* __restrict__ A,
                                                const float* __restrict__ B,
                                                const float* __restrict__ add,
                                                float* __restrict__ C,
                                                int M, int N, int K, int act) {
  __shared__ float As[16][68];
  __shared__ float Bs[16][68];
  const int bm = blockIdx.x * 64;
  const int bn = blockIdx.y * 64;
  const int tid = threadIdx.x;
  const int tm = tid >> 4, tn = tid & 15;
  const int lk = (tid & 3) << 2, lm = tid >> 2;
  float acc[4][4] = {{0.f}};
  const int ar = bm + lm;
  const int br = bn + lm;
  for (int k0 = 0; k0 < K; k0 += 16) {
    float4 a4 = make_float4(0.f, 0.f, 0.f, 0.f);
    float4 b4 = make_float4(0.f, 0.f, 0.f, 0.f);
    if (ar < M) a4 = *(const float4*)(A + (size_t)ar * K + k0 + lk);
    if (br < N) b4 = *(const float4*)(B + (size_t)br * K + k0 + lk);
    __syncthreads();
    As[lk][lm] = a4.x; As[lk + 1][lm] = a4.y; As[lk + 2][lm] = a4.z; As[lk + 3][lm] = a4.w;
    Bs[lk][lm] = b4.x; Bs[lk + 1][lm] = b4.y; Bs[lk + 2][lm] = b4.z; Bs[lk + 3][lm] = b4.w;
    __syncthreads();
#pragma unroll
    for (int kk = 0; kk < 16; ++kk) {
      float4 av = *(const float4*)&As[kk][tm << 2];
      float4 bv = *(const float4*)&Bs[kk][tn << 2];
      float a_[4] = {av.x, av.y, av.z, av.w};
      float b_[4] = {bv.x, bv.y, bv.z, bv.w};
#pragma unroll
      for (int i = 0; i < 4; ++i)
#pragma unroll
        for (int j = 0; j < 4; ++j) acc[i][j] = fmaf(a_[i], b_[j], acc[i][j]);
    }
  }
#pragma unroll
  for (int i = 0; i < 4; ++i) {
    int row = bm + (tm << 2) + i;
    if (row >= M) continue;
#pragma unroll
    for (int j = 0; j < 4; ++j) {
      int col = bn + (tn << 2) + j;
      if (col >= N) continue;
      float r = acc[i][j];
      if (add) r += add[(size_t)row * N + col];
      if (act == 1) r = 1.0f / (1.0f + expf(-r));
      else if (act == 2) r = r / (1.0f + expf(-r));
      C[(size_t)row * N + col] = r;
    }
  }
}

// ---------------- activations: v=silu, a1=silu, beta=sigmoid ----------------
__global__ void act_split(const float* __restrict__ C1, float* __restrict__ vb,
                          float* __restrict__ a1s, float* __restrict__ betab) {
  int idx = blockIdx.x * 256 + threadIdx.x;
  if (idx >= T_SEQ * 193) return;
  int t = idx / 193, j = idx % 193;
  if (j < 64) {
    float x = C1[(size_t)t * C1LD + 128 + j];
    vb[(size_t)t * DV + j] = siluf_(x);
  } else if (j < 192) {
    float x = C1[(size_t)t * C1LD + 192 + (j - 64)];
    a1s[(size_t)t * DKP + (j - 64)] = siluf_(x);
  } else {
    betab[t] = sigmoidf_(C1[(size_t)t * C1LD + 320]);
  }
}

// ---------------- PoPE: f32 phase arithmetic (matches numpy), accurate trig ----------------
__global__ __launch_bounds__(256) void pope_kernel(const float* __restrict__ C1,
                                                   const float* __restrict__ freq,
                                                   const float* __restrict__ shift,
                                                   float* __restrict__ qb, float* __restrict__ kb) {
  int idx = blockIdx.x * 256 + threadIdx.x;
  if (idx >= T_SEQ * DK) return;
  int t = idx >> 6;
  int i = idx & 63;
  const double TWO_PI = 6.283185307179586476925286766559;
  const double INV_TWO_PI = 0.15915494309189533576888376337251;
  float phiq = (float)t * freq[i];          // f32 multiply (matches numpy)
  float phik = phiq + shift[i];             // f32 add (matches numpy)
  float xq = C1[(size_t)t * C1LD + i];
  float muq = xq > 15.f ? xq : log1pf(expf(xq));
  double w = (double)phiq * INV_TWO_PI;
  w -= floor(w);
  float aq = (float)(w * TWO_PI);
  qb[(size_t)t * DKP + i] = muq * cosf(aq);
  qb[(size_t)t * DKP + 64 + i] = muq * sinf(aq);
  float xk = C1[(size_t)t * C1LD + DK + i];
  float muk = xk > 15.f ? xk : log1pf(expf(xk));
  double wk = (double)phik * INV_TWO_PI;
  wk -= floor(wk);
  float ak = (float)(wk * TWO_PI);
  kb[(size_t)t * DKP + i] = muk * cosf(ak);
  kb[(size_t)t * DKP + 64 + i] = muk * sinf(ak);
}

// ================= chunked scan =================
// Pass A: per (chunk, cc): cc<128 -> basis column e_cc (transition), cc>=128 -> driven col.
__global__ __launch_bounds__(64) void scan_passA(const float* __restrict__ kb,
                                                 const float* __restrict__ alphab,
                                                 const float* __restrict__ vb,
                                                 const float* __restrict__ betab,
                                                 float* __restrict__ PT,
                                                 float* __restrict__ fstate) {
  const int chunk = blockIdx.x;
  const int cc = blockIdx.y;  // 0..191
  const int l = threadIdx.x;
  const bool isP = cc < 128;
  const int c = isP ? 0 : (cc - 128);
  const float2* k2 = (const float2*)kb + (size_t)chunk * CHUNK * 64;
  const float2* a2 = (const float2*)alphab + (size_t)chunk * CHUNK * 64;
  const float* vcol = vb + (size_t)chunk * CHUNK * 64 + c;
  const float* bp = betab + (size_t)chunk * CHUNK;
  float s0, s1;
  if (isP) {
    s0 = (2 * l == cc) ? 1.f : 0.f;
    s1 = (2 * l + 1 == cc) ? 1.f : 0.f;
  } else {
    s0 = 0.f; s1 = 0.f;
  }
  float2 kv = k2[l], av = a2[l];
  float vt = isP ? 0.f : vcol[0];
  float bt = bp[0];
  for (int t = 0; t < CHUNK; ++t) {
    int tn = (t + 1 < CHUNK) ? t + 1 : CHUNK - 1;
    float2 kn = k2[(size_t)tn * 64 + l];
    float2 an = a2[(size_t)tn * 64 + l];
    float vn = isP ? 0.f : vcol[(size_t)tn * 64];
    float bn = bp[tn];
    s0 *= av.x; s1 *= av.y;
    float dot = wave_sum(kv.x * s0 + kv.y * s1);
    float cf = bt * (vt - dot);
    s0 = fmaf(cf, kv.x, s0);
    s1 = fmaf(cf, kv.y, s1);
    kv = kn; av = an; vt = vn; bt = bn;
  }
  if (isP) {
    float2* dst = (float2*)(PT + (size_t)chunk * 16384 + (size_t)cc * 128);
    dst[l] = make_float2(s0, s1);
  } else {
    fstate[(size_t)chunk * 8192 + (size_t)(2 * l) * 64 + c] = s0;
    fstate[(size_t)chunk * 8192 + (size_t)(2 * l + 1) * 64 + c] = s1;
  }
}

// Combine v2: 256 threads = 2 K-halves x 128 rows; 4 independent FMA chains per thread.
__global__ __launch_bounds__(256) void scan_combine(const float* __restrict__ PT,
                                                    const float* __restrict__ fstate,
                                                    float* __restrict__ sinbuf) {
  const int c = blockIdx.x;            // 0..63
  const int r = threadIdx.x & 127;     // row
  const int h = threadIdx.x >> 7;      // K-half
  __shared__ float sv[128];
  __shared__ float part[128];
  float s = 0.f;
  for (int j = 0; j < NCHUNK; ++j) {
    if (h == 0) {
      sinbuf[(size_t)j * 8192 + (size_t)r * 64 + c] = s;
      sv[r] = s;
    }
    __syncthreads();
    const float* Pj = PT + (size_t)j * 16384 + (size_t)h * 64 * 128;
    const float* svh = sv + h * 64;
    float a0 = (h == 0) ? fstate[(size_t)j * 8192 + (size_t)r * 64 + c] : 0.f;
    float a1 = 0.f, a2 = 0.f, a3 = 0.f;
#pragma unroll
    for (int jj = 0; jj < 64; jj += 4) {
      a0 = fmaf(Pj[(size_t)(jj    ) * 128 + r], svh[jj    ], a0);
      a1 = fmaf(Pj[(size_t)(jj + 1) * 128 + r], svh[jj + 1], a1);
      a2 = fmaf(Pj[(size_t)(jj + 2) * 128 + r], svh[jj + 2], a2);
      a3 = fmaf(Pj[(size_t)(jj + 3) * 128 + r], svh[jj + 3], a3);
    }
    float tot = (a0 + a1) + (a2 + a3);
    if (h == 1) part[r] = tot;
    __syncthreads();
    if (h == 0) s = tot + part[r];
  }
}

// Pass B: exact per-column scan per chunk with true incoming state; emits outputs.
__global__ __launch_bounds__(64) void scan_passB(const float* __restrict__ qb,
                                                 const float* __restrict__ kb,
                                                 const float* __restrict__ alphab,
                                                 const float* __restrict__ vb,
                                                 const float* __restrict__ betab,
                                                 const float* __restrict__ sinbuf,
                                                 float* __restrict__ ob) {
  const int chunk = blockIdx.x;
  const int c = blockIdx.y;  // 0..63
  const int l = threadIdx.x;
  const float2* k2 = (const float2*)kb + (size_t)chunk * CHUNK * 64;
  const float2* a2 = (const float2*)alphab + (size_t)chunk * CHUNK * 64;
  const float2* q2 = (const float2*)qb + (size_t)chunk * CHUNK * 64;
  const float* vcol = vb + (size_t)chunk * CHUNK * 64 + c;
  const float* bp = betab + (size_t)chunk * CHUNK;
  float* ocol = ob + (size_t)chunk * CHUNK * 64 + c;
  float s0 = sinbuf[(size_t)chunk * 8192 + (size_t)(2 * l) * 64 + c];
  float s1 = sinbuf[(size_t)chunk * 8192 + (size_t)(2 * l + 1) * 64 + c];
  float2 kv = k2[l], av = a2[l], qv = q2[l];
  float vt = vcol[0], bt = bp[0];
  for (int t = 0; t < CHUNK; ++t) {
    int tn = (t + 1 < CHUNK) ? t + 1 : CHUNK - 1;
    float2 kn = k2[(size_t)tn * 64 + l];
    float2 an = a2[(size_t)tn * 64 + l];
    float2 qn = q2[(size_t)tn * 64 + l];
    float vn = vcol[(size_t)tn * 64];
    float bn = bp[tn];
    s0 *= av.x; s1 *= av.y;
    float dot = wave_sum(kv.x * s0 + kv.y * s1);
    float cf = bt * (vt - dot);
    s0 = fmaf(cf, kv.x, s0);
    s1 = fmaf(cf, kv.y, s1);
    float osum = wave_sum(qv.x * s0 + qv.y * s1);
    if (l == 0) ocol[(size_t)t * 64] = osum;
    kv = kn; av = an; qv = qn; vt = vn; bt = bn;
  }
}

// ---------------- post: og16 = bf16(rmsnorm(o)*pnw*sigmoid(gate_pre)) ----------------
__global__ __launch_bounds__(256) void post_kernel(const float* __restrict__ ob,
                                                   const float* __restrict__ C1,
                                                   const float* __restrict__ pnw,
                                                   unsigned short* __restrict__ og16) {
  int row = blockIdx.x * 4 + (threadIdx.x >> 6);
  int c = threadIdx.x & 63;
  float o = ob[(size_t)row * DV + c];
  float ss = wave_sum(o * o);
  float scale = 1.0f / sqrtf(ss * (1.0f / DV) + RMS_EPS);
  float g = sigmoidf_(C1[(size_t)row * C1LD + 321 + c]);
  og16[(size_t)row * DV + c] = f2bf(o * scale * pnw[c] * g);
}

// ---------------- rmsnorm over d=1024 rows -> bf16 ----------------
__global__ __launch_bounds__(256) void rmsnorm_rows(const float* __restrict__ x,
                                                    const float* __restrict__ w,
                                                    unsigned short* __restrict__ y) {
  int row = blockIdx.x;
  const float4* x4 = (const float4*)(x + (size_t)row * D_MODEL);
  const float4* w4 = (const float4*)w;
  float4 v = x4[threadIdx.x];
  float ss = v.x * v.x + v.y * v.y + v.z * v.z + v.w * v.w;
  ss = wave_sum(ss);
  __shared__ float red[4];
  if ((threadIdx.x & 63) == 0) red[threadIdx.x >> 6] = ss;
  __syncthreads();
  float tot = red[0] + red[1] + red[2] + red[3];
  float scale = 1.0f / sqrtf(tot * (1.0f / D_MODEL) + RMS_EPS);
  float4 wv = w4[threadIdx.x];
  uint2 o;
  o.x = (unsigned)f2bf(v.x * scale * wv.x) | ((unsigned)f2bf(v.y * scale * wv.y) << 16);
  o.y = (unsigned)f2bf(v.z * scale * wv.z) | ((unsigned)f2bf(v.w * scale * wv.w) << 16);
  ((uint2*)(y + (size_t)row * D_MODEL))[threadIdx.x] = o;
}

// ---------------- GU16 = bf16(G * U) ----------------
__global__ void mul_to_bf16(const float* __restrict__ G, const float* __restrict__ U,
                            unsigned short* __restrict__ O, int n4) {
  int i = blockIdx.x * 256 + threadIdx.x;
  if (i >= n4) return;
  float4 g = ((const float4*)G)[i];
  float4 u = ((const float4*)U)[i];
  uint2 o;
  o.x = (unsigned)f2bf(g.x * u.x) | ((unsigned)f2bf(g.y * u.y) << 16);
  o.y = (unsigned)f2bf(g.z * u.z) | ((unsigned)f2bf(g.w * u.w) << 16);
  ((uint2*)O)[i] = o;
}

extern "C" void kernel_launch(void* const* d_in, const int* in_sizes, int n_in,
                              void* d_out, int out_size, void* d_ws, size_t ws_size,
                              hipStream_t stream) {
  const float* x_seq = (const float*)d_in[0];
  const float* W_q = (const float*)d_in[1];
  const float* W_k = (const float*)d_in[2];
  const float* W_v = (const float*)d_in[3];
  const float* pope_delta = (const float*)d_in[4];
  const float* W_a1 = (const float*)d_in[5];
  const float* W_a2 = (const float*)d_in[6];
  const float* W_beta = (const float*)d_in[7];
  const float* pnw = (const float*)d_in[8];
  const float* out_gate_W = (const float*)d_in[9];
  const float* W_out = (const float*)d_in[10];
  const float* ffn_norm_w = (const float*)d_in[11];
  const float* Wg = (const float*)d_in[12];
  const float* Wu = (const float*)d_in[13];
  const float* Wd = (const float*)d_in[14];
  float* out = (float*)d_out;

  float* F = (float*)d_ws;
  float* freq_f = F;                      // 64
  float* shift_f = F + 64;                // 64
  size_t o = 256;
  unsigned short* Wcat16 = (unsigned short*)(F + o); o += 262144;   // 512x1024 bf16
  unsigned short* Wg16   = (unsigned short*)(F + o); o += 524288;   // 1024x1024 bf16
  unsigned short* Wu16   = (unsigned short*)(F + o); o += 524288;
  unsigned short* Wd16   = (unsigned short*)(F + o); o += 524288;
  unsigned short* Wout16 = (unsigned short*)(F + o); o += 32768;    // 1024x64 bf16
  unsigned short* og16   = (unsigned short*)(F + o); o += 262144;   // 8192x64 bf16
  float* BIG = F + o;   // o = 2,130,176
  // phase 1 layout (within BIG)
  float* C1 = BIG;                        // 8192x512 f32
  float* qb = C1 + 4194304;               // 8192x128
  float* kb = qb + 1048576;
  float* alphab = kb + 1048576;
  float* a1s = alphab + 1048576;
  float* vb = a1s + 1048576;              // 8192x64
  float* betab = vb + 524288;             // 8192
  float* ob = betab + 8192;               // 8192x64
  float* PT = ob + 524288;                // 64x128x128
  float* fstate = PT + 1048576;           // 64x128x64
  float* sinbuf = fstate + 524288;        // 64x128x64
  unsigned short* x16 = (unsigned short*)(sinbuf + 524288);  // 8192x1024 bf16 (4,194,304 f)
  // phase 2 layout (reuses BIG; phase-1 buffers dead by then)
  unsigned short* hb16 = (unsigned short*)BIG;   // 8192x1024 bf16
  unsigned short* GU16 = (unsigned short*)BIG;   // aliases hb16 (hb16 dead after Wu GEMM)
  float* Gb = BIG + 4194304;              // 8192x1024 f32
  float* Ub = Gb + 8388608;               // 8192x1024 f32

  (void)in_sizes; (void)n_in; (void)out_size; (void)ws_size;

  init_tables<<<1, 64, 0, stream>>>(pope_delta, freq_f, shift_f);
  build_wcat16<<<(512 * 1024 + 255) / 256, 256, 0, stream>>>(W_q, W_k, W_v, W_a1, W_beta,
                                                             out_gate_W, Wcat16);
  conv_bf16<<<(2097152 + 255) / 256, 256, 0, stream>>>(x_seq, x16, 2097152);
  conv_bf16<<<(262144 + 255) / 256, 256, 0, stream>>>(Wg, Wg16, 262144);
  conv_bf16<<<(262144 + 255) / 256, 256, 0, stream>>>(Wu, Wu16, 262144);
  conv_bf16<<<(262144 + 255) / 256, 256, 0, stream>>>(Wd, Wd16, 262144);
  conv_bf16<<<(16384 + 255) / 256, 256, 0, stream>>>(W_out, Wout16, 16384);
  // fused projection: C1 = x16 @ Wcat16^T  (8192 x 512, K=1024)
  gemm_bf16<<<dim3(64, 4), 256, 0, stream>>>(x16, Wcat16, nullptr, C1, T_SEQ, 512, 1024, 0);
  act_split<<<(T_SEQ * 193 + 255) / 256, 256, 0, stream>>>(C1, vb, a1s, betab);
  gemm_f32<<<dim3(128, 2), 256, 0, stream>>>(a1s, W_a2, nullptr, alphab, T_SEQ, DKP, DKP, 1);
  pope_kernel<<<(T_SEQ * DK + 255) / 256, 256, 0, stream>>>(C1, freq_f, shift_f, qb, kb);
  // chunked scan
  scan_passA<<<dim3(NCHUNK, 192), 64, 0, stream>>>(kb, alphab, vb, betab, PT, fstate);
  scan_combine<<<64, 256, 0, stream>>>(PT, fstate, sinbuf);
  scan_passB<<<dim3(NCHUNK, 64), 64, 0, stream>>>(qb, kb, alphab, vb, betab, sinbuf, ob);
  post_kernel<<<T_SEQ / 4, 256, 0, stream>>>(ob, C1, pnw, og16);
  // xres = x_seq + og @ W_out^T  (8192 x 1024, K=64) -> d_out
  gemm_bf16<<<dim3(64, 8), 256, 0, stream>>>(og16, Wout16, x_seq, out, T_SEQ, D_MODEL, 64, 0);
  rmsnorm_rows<<<T_SEQ, 256, 0, stream>>>(out, ffn_norm_w, hb16);
  // FFN
  gemm_bf16<<<dim3(64, 8), 256, 0, stream>>>(hb16, Wg16, nullptr, Gb, T_SEQ, D_MODEL, D_MODEL, 2);
  gemm_bf16<<<dim3(64, 8), 256, 0, stream>>>(hb16, Wu16, nullptr, Ub, T_SEQ, D_MODEL, D_MODEL, 0);
  mul_to_bf16<<<(2097152 + 255) / 256, 256, 0, stream>>>(Gb, Ub, GU16, 2097152);
  gemm_bf16<<<dim3(64, 8), 256, 0, stream>>>(GU16, Wd16, out, out, T_SEQ, D_MODEL, D_MODEL, 0);
}

// Round 6
// 624.984 us; speedup vs baseline: 9.9846x; 1.0051x over previous
//
#include <hip/hip_runtime.h>
#include <math.h>

#define T_SEQ 8192
#define D_MODEL 1024
#define DK 64
#define DKP 128
#define DV 64
#define C1LD 512   // padded fused-projection width (385 -> 512)
#define RMS_EPS 1.1920929e-07f
#define CHUNK 128
#define NCHUNK 64  // T_SEQ / CHUNK

typedef __attribute__((ext_vector_type(8))) __bf16 bf16x8;
typedef __attribute__((ext_vector_type(4))) float f32x4;

__device__ __forceinline__ float wave_sum(float x) {
#pragma unroll
  for (int off = 1; off < 64; off <<= 1) x += __shfl_xor(x, off, 64);
  return x;
}

__device__ __forceinline__ float sigmoidf_(float x) { return 1.0f / (1.0f + expf(-x)); }
__device__ __forceinline__ float siluf_(float x) { return x / (1.0f + expf(-x)); }

__device__ __forceinline__ unsigned short f2bf(float f) {
  unsigned u = __float_as_uint(f);
  u += 0x7fff + ((u >> 16) & 1);  // RNE
  return (unsigned short)(u >> 16);
}

// ---------------- tables: f32 freq and f32 k-phase shift (match numpy f32 semantics) ------
__global__ void init_tables(const float* __restrict__ delta, float* __restrict__ freq,
                            float* __restrict__ shift) {
  int i = threadIdx.x;  // 64
  freq[i] = (float)pow(10000.0, (double)i / 64.0);
  float s = 1.0f / (1.0f + expf(-delta[i]));
  shift[i] = -6.2831855f * s;
}

// ---------------- concat weights (bf16, padded to 512 rows) ----------------
__global__ void build_wcat16(const float* __restrict__ Wq, const float* __restrict__ Wk,
                             const float* __restrict__ Wv, const float* __restrict__ Wa1,
                             const float* __restrict__ Wb, const float* __restrict__ Wg,
                             unsigned short* __restrict__ W16) {
  int idx = blockIdx.x * 256 + threadIdx.x;
  if (idx >= 512 * 1024) return;
  int row = idx >> 10, col = idx & 1023;
  float v = 0.f;
  if (row < 64) v = Wq[row * 1024 + col];
  else if (row < 128) v = Wk[(row - 64) * 1024 + col];
  else if (row < 192) v = Wv[(row - 128) * 1024 + col];
  else if (row < 320) v = Wa1[(row - 192) * 1024 + col];
  else if (row == 320) v = Wb[col];
  else if (row < 385) v = Wg[(row - 321) * 1024 + col];
  W16[idx] = f2bf(v);
}

// ---------------- f32 -> bf16 convert (float4 -> 4x bf16) ----------------
__global__ void conv_bf16(const float* __restrict__ in, unsigned short* __restrict__ out,
                          int n4) {
  int i = blockIdx.x * 256 + threadIdx.x;
  if (i >= n4) return;
  float4 v = ((const float4*)in)[i];
  uint2 o;
  o.x = (unsigned)f2bf(v.x) | ((unsigned)f2bf(v.y) << 16);
  o.y = (unsigned)f2bf(v.z) | ((unsigned)f2bf(v.w) << 16);
  ((uint2*)out)[i] = o;
}

// ---------------- fused weight conversions (Wg, Wu, Wd, W_out) ----------------
__global__ void conv_weights(const float* __restrict__ Wg, const float* __restrict__ Wu,
                             const float* __restrict__ Wd, const float* __restrict__ Wo,
                             unsigned short* __restrict__ Wg16, unsigned short* __restrict__ Wu16,
                             unsigned short* __restrict__ Wd16, unsigned short* __restrict__ Wo16) {
  int i = blockIdx.x * 256 + threadIdx.x;  // float4 groups
  const float* src;
  unsigned short* dst;
  int base;
  if (i < 262144) { src = Wg; dst = Wg16; base = i; }
  else if (i < 524288) { src = Wu; dst = Wu16; base = i - 262144; }
  else if (i < 786432) { src = Wd; dst = Wd16; base = i - 524288; }
  else if (i < 802816) { src = Wo; dst = Wo16; base = i - 786432; }
  else return;
  float4 v = ((const float4*)src)[base];
  uint2 o;
  o.x = (unsigned)f2bf(v.x) | ((unsigned)f2bf(v.y) << 16);
  o.y = (unsigned)f2bf(v.z) | ((unsigned)f2bf(v.w) << 16);
  ((uint2*)dst)[base] = o;
}

// ---------------- bf16 MFMA GEMM (m97 structure): C(f32) = act(A @ B^T [+ add]) ----------
// A: M x K bf16 row-major, B: N x K bf16 row-major. M%128==0, N%128==0, K%32==0.
// 128x128 tile, BK=32, 256 threads = 4 waves (2x2 of 64x64). Staging via
// global_load_lds width 16: LDS dest = wave-uniform base + lane*16 (linear layout),
// global source per-lane. act: 0 none, 2 silu.
__global__ __launch_bounds__(256) void gemm_bf16(const unsigned short* __restrict__ A,
                                                 const unsigned short* __restrict__ B,
                                                 const float* __restrict__ add,
                                                 float* __restrict__ C,
                                                 int M, int N, int K, int act) {
  __shared__ unsigned short As[128 * 32];
  __shared__ unsigned short Bs[128 * 32];
  const int tid = threadIdx.x;
  const int tm0 = blockIdx.x * 128, tn0 = blockIdx.y * 128;
  const int lane = tid & 63;
  const int w = tid >> 6;
  const int wr = (w >> 1) * 64, wc = (w & 1) * 64;
  const int fr = lane & 15, fq = lane >> 4;
  const int seg = w << 5;              // wave's 32-row segment of the tile
  const int srow = lane >> 2;          // 0..15 within a 16-row staging call
  const int skc = (lane & 3) * 8;      // k element offset (8 bf16 = 16 B)
  f32x4 acc[4][4];
#pragma unroll
  for (int a = 0; a < 4; ++a)
#pragma unroll
    for (int b = 0; b < 4; ++b) acc[a][b] = (f32x4){0.f, 0.f, 0.f, 0.f};

  for (int k0 = 0; k0 < K; k0 += 32) {
    __syncthreads();  // prior iteration's ds_reads done before overwrite
#pragma unroll
    for (int j = 0; j < 2; ++j) {
      int r = seg + j * 16 + srow;
      __builtin_amdgcn_global_load_lds(
          (const __attribute__((address_space(1))) unsigned int*)(A + (size_t)(tm0 + r) * K + k0 + skc),
          (__attribute__((address_space(3))) unsigned int*)(As + (seg + j * 16) * 32),
          16, 0, 0);
      __builtin_amdgcn_global_load_lds(
          (const __attribute__((address_space(1))) unsigned int*)(B + (size_t)(tn0 + r) * K + k0 + skc),
          (__attribute__((address_space(3))) unsigned int*)(Bs + (seg + j * 16) * 32),
          16, 0, 0);
    }
    __syncthreads();  // compiler emits vmcnt(0) drain before barrier
    bf16x8 af[4], bfr[4];
#pragma unroll
    for (int a = 0; a < 4; ++a)
      af[a] = *(const bf16x8*)(As + (wr + a * 16 + fr) * 32 + fq * 8);
#pragma unroll
    for (int b = 0; b < 4; ++b)
      bfr[b] = *(const bf16x8*)(Bs + (wc + b * 16 + fr) * 32 + fq * 8);
#pragma unroll
    for (int a = 0; a < 4; ++a)
#pragma unroll
      for (int b = 0; b < 4; ++b)
        acc[a][b] = __builtin_amdgcn_mfma_f32_16x16x32_bf16(af[a], bfr[b], acc[a][b], 0, 0, 0);
  }
  // epilogue: D row = tm0+wr+a*16+fq*4+r, col = tn0+wc+b*16+fr
#pragma unroll
  for (int a = 0; a < 4; ++a) {
#pragma unroll
    for (int b = 0; b < 4; ++b) {
#pragma unroll
      for (int r = 0; r < 4; ++r) {
        int row = tm0 + wr + a * 16 + fq * 4 + r;
        int col = tn0 + wc + b * 16 + fr;
        float v = acc[a][b][r];
        if (add) v += add[(size_t)row * N + col];
        if (act == 2) v = v / (1.0f + expf(-v));
        C[(size_t)row * N + col] = v;
      }
    }
  }
}

// ---------------- generic f32 GEMM (kept for the small alpha2 GEMM) ----------------
__global__ __launch_bounds__(256) void gemm_f32(const float* __restrict__ A,
                                                const float* __restrict__ B,
                                                const float* __restrict__ add,
                                                float* __restrict__ C,
                                                int M, int N, int K, int act) {
  __shared__ float As[16][68];
  __shared__ float Bs[16][68];
  const int bm = blockIdx.x * 64;
  const int bn = blockIdx.y * 64;
  const int tid = threadIdx.x;
  const int tm = tid >> 4, tn = tid & 15;
  const int lk = (tid & 3) << 2, lm = tid >> 2;
  float acc[4][4] = {{0.f}};
  const int ar = bm + lm;
  const int br = bn + lm;
  for (int k0 = 0; k0 < K; k0 += 16) {
    float4 a4 = make_float4(0.f, 0.f, 0.f, 0.f);
    float4 b4 = make_float4(0.f, 0.f, 0.f, 0.f);
    if (ar < M) a4 = *(const float4*)(A + (size_t)ar * K + k0 + lk);
    if (br < N) b4 = *(const float4*)(B + (size_t)br * K + k0 + lk);
    __syncthreads();
    As[lk][lm] = a4.x; As[lk + 1][lm] = a4.y; As[lk + 2][lm] = a4.z; As[lk + 3][lm] = a4.w;
    Bs[lk][lm] = b4.x; Bs[lk + 1][lm] = b4.y; Bs[lk + 2][lm] = b4.z; Bs[lk + 3][lm] = b4.w;
    __syncthreads();
#pragma unroll
    for (int kk = 0; kk < 16; ++kk) {
      float4 av = *(const float4*)&As[kk][tm << 2];
      float4 bv = *(const float4*)&Bs[kk][tn << 2];
      float a_[4] = {av.x, av.y, av.z, av.w};
      float b_[4] = {bv.x, bv.y, bv.z, bv.w};
#pragma unroll
      for (int i = 0; i < 4; ++i)
#pragma unroll
        for (int j = 0; j < 4; ++j) acc[i][j] = fmaf(a_[i], b_[j], acc[i][j]);
    }
  }
#pragma unroll
  for (int i = 0; i < 4; ++i) {
    int row = bm + (tm << 2) + i;
    if (row >= M) continue;
#pragma unroll
    for (int j = 0; j < 4; ++j) {
      int col = bn + (tn << 2) + j;
      if (col >= N) continue;
      float r = acc[i][j];
      if (add) r += add[(size_t)row * N + col];
      if (act == 1) r = 1.0f / (1.0f + expf(-r));
      else if (act == 2) r = r / (1.0f + expf(-r));
      C[(size_t)row * N + col] = r;
    }
  }
}

// ---------------- activations: v=silu, a1=silu, beta=sigmoid ----------------
__global__ void act_split(const float* __restrict__ C1, float* __restrict__ vb,
                          float* __restrict__ a1s, float* __restrict__ betab) {
  int idx = blockIdx.x * 256 + threadIdx.x;
  if (idx >= T_SEQ * 193) return;
  int t = idx / 193, j = idx % 193;
  if (j < 64) {
    float x = C1[(size_t)t * C1LD + 128 + j];
    vb[(size_t)t * DV + j] = siluf_(x);
  } else if (j < 192) {
    float x = C1[(size_t)t * C1LD + 192 + (j - 64)];
    a1s[(size_t)t * DKP + (j - 64)] = siluf_(x);
  } else {
    betab[t] = sigmoidf_(C1[(size_t)t * C1LD + 320]);
  }
}

// ---------------- PoPE: f32 phase arithmetic (matches numpy), accurate trig ----------------
__global__ __launch_bounds__(256) void pope_kernel(const float* __restrict__ C1,
                                                   const float* __restrict__ freq,
                                                   const float* __restrict__ shift,
                                                   float* __restrict__ qb, float* __restrict__ kb) {
  int idx = blockIdx.x * 256 + threadIdx.x;
  if (idx >= T_SEQ * DK) return;
  int t = idx >> 6;
  int i = idx & 63;
  const double TWO_PI = 6.283185307179586476925286766559;
  const double INV_TWO_PI = 0.15915494309189533576888376337251;
  float phiq = (float)t * freq[i];          // f32 multiply (matches numpy)
  float phik = phiq + shift[i];             // f32 add (matches numpy)
  float xq = C1[(size_t)t * C1LD + i];
  float muq = xq > 15.f ? xq : log1pf(expf(xq));
  double w = (double)phiq * INV_TWO_PI;
  w -= floor(w);
  float aq = (float)(w * TWO_PI);
  qb[(size_t)t * DKP + i] = muq * cosf(aq);
  qb[(size_t)t * DKP + 64 + i] = muq * sinf(aq);
  float xk = C1[(size_t)t * C1LD + DK + i];
  float muk = xk > 15.f ? xk : log1pf(expf(xk));
  double wk = (double)phik * INV_TWO_PI;
  wk -= floor(wk);
  float ak = (float)(wk * TWO_PI);
  kb[(size_t)t * DKP + i] = muk * cosf(ak);
  kb[(size_t)t * DKP + 64 + i] = muk * sinf(ak);
}

// ================= chunked scan =================
// Pass A, 3 columns/wave: basis columns y and y+64 (unit init), driven column y (zero init).
// Per-column op sequence is bit-identical to the 1-col version; 3 independent shuffle
// chains per wave give ILP to cover shfl latency.
__global__ __launch_bounds__(64) void scan_passA(const float* __restrict__ kb,
                                                 const float* __restrict__ alphab,
                                                 const float* __restrict__ vb,
                                                 const float* __restrict__ betab,
                                                 float* __restrict__ PT,
                                                 float* __restrict__ fstate) {
  const int chunk = blockIdx.x;
  const int y = blockIdx.y;  // 0..63
  const int l = threadIdx.x;
  const float2* k2 = (const float2*)kb + (size_t)chunk * CHUNK * 64;
  const float2* a2 = (const float2*)alphab + (size_t)chunk * CHUNK * 64;
  const float* vcol = vb + (size_t)chunk * CHUNK * 64 + y;
  const float* bp = betab + (size_t)chunk * CHUNK;
  float p0a = (2 * l == y) ? 1.f : 0.f, p0b = (2 * l + 1 == y) ? 1.f : 0.f;
  float p1a = (2 * l == y + 64) ? 1.f : 0.f, p1b = (2 * l + 1 == y + 64) ? 1.f : 0.f;
  float da = 0.f, db = 0.f;
  float2 kv = k2[l], av = a2[l];
  float vt = vcol[0], bt = bp[0];
  for (int t = 0; t < CHUNK; ++t) {
    int tn = (t + 1 < CHUNK) ? t + 1 : CHUNK - 1;
    float2 kn = k2[(size_t)tn * 64 + l];
    float2 an = a2[(size_t)tn * 64 + l];
    float vn = vcol[(size_t)tn * 64];
    float bn = bp[tn];
    p0a *= av.x; p0b *= av.y;
    p1a *= av.x; p1b *= av.y;
    da *= av.x;  db *= av.y;
    float d0 = kv.x * p0a + kv.y * p0b;
    float d1 = kv.x * p1a + kv.y * p1b;
    float d2 = kv.x * da + kv.y * db;
#pragma unroll
    for (int off = 1; off < 64; off <<= 1) {
      d0 += __shfl_xor(d0, off, 64);
      d1 += __shfl_xor(d1, off, 64);
      d2 += __shfl_xor(d2, off, 64);
    }
    float c0 = bt * (0.f - d0);
    float c1 = bt * (0.f - d1);
    float c2 = bt * (vt - d2);
    p0a = fmaf(c0, kv.x, p0a); p0b = fmaf(c0, kv.y, p0b);
    p1a = fmaf(c1, kv.x, p1a); p1b = fmaf(c1, kv.y, p1b);
    da = fmaf(c2, kv.x, da);   db = fmaf(c2, kv.y, db);
    kv = kn; av = an; vt = vn; bt = bn;
  }
  float2* dst0 = (float2*)(PT + (size_t)chunk * 16384 + (size_t)y * 128);
  dst0[l] = make_float2(p0a, p0b);
  float2* dst1 = (float2*)(PT + (size_t)chunk * 16384 + (size_t)(y + 64) * 128);
  dst1[l] = make_float2(p1a, p1b);
  fstate[(size_t)chunk * 8192 + (size_t)(2 * l) * 64 + y] = da;
  fstate[(size_t)chunk * 8192 + (size_t)(2 * l + 1) * 64 + y] = db;
}

// Combine: per column c, sequentially s_in(j+1) = P_j s_in(j) + f_j. 2 K-halves x 128 rows.
__global__ __launch_bounds__(256) void scan_combine(const float* __restrict__ PT,
                                                    const float* __restrict__ fstate,
                                                    float* __restrict__ sinbuf) {
  const int c = blockIdx.x;            // 0..63
  const int r = threadIdx.x & 127;     // row
  const int h = threadIdx.x >> 7;      // K-half
  __shared__ float sv[128];
  __shared__ float part[128];
  float s = 0.f;
  for (int j = 0; j < NCHUNK; ++j) {
    if (h == 0) {
      sinbuf[(size_t)j * 8192 + (size_t)r * 64 + c] = s;
      sv[r] = s;
    }
    __syncthreads();
    const float* Pj = PT + (size_t)j * 16384 + (size_t)h * 64 * 128;
    const float* svh = sv + h * 64;
    float a0 = (h == 0) ? fstate[(size_t)j * 8192 + (size_t)r * 64 + c] : 0.f;
    float a1 = 0.f, a2 = 0.f, a3 = 0.f;
#pragma unroll
    for (int jj = 0; jj < 64; jj += 4) {
      a0 = fmaf(Pj[(size_t)(jj) * 128 + r], svh[jj], a0);
      a1 = fmaf(Pj[(size_t)(jj + 1) * 128 + r], svh[jj + 1], a1);
      a2 = fmaf(Pj[(size_t)(jj + 2) * 128 + r], svh[jj + 2], a2);
      a3 = fmaf(Pj[(size_t)(jj + 3) * 128 + r], svh[jj + 3], a3);
    }
    float tot = (a0 + a1) + (a2 + a3);
    if (h == 1) part[r] = tot;
    __syncthreads();
    if (h == 0) s = tot + part[r];
  }
}

// Pass B, 2 columns/wave: exact per-column scan with true incoming state; emits outputs.
__global__ __launch_bounds__(64) void scan_passB(const float* __restrict__ qb,
                                                 const float* __restrict__ kb,
                                                 const float* __restrict__ alphab,
                                                 const float* __restrict__ vb,
                                                 const float* __restrict__ betab,
                                                 const float* __restrict__ sinbuf,
                                                 float* __restrict__ ob) {
  const int chunk = blockIdx.x;
  const int y = blockIdx.y;  // 0..31 -> columns y and y+32
  const int l = threadIdx.x;
  const float2* k2 = (const float2*)kb + (size_t)chunk * CHUNK * 64;
  const float2* a2 = (const float2*)alphab + (size_t)chunk * CHUNK * 64;
  const float2* q2 = (const float2*)qb + (size_t)chunk * CHUNK * 64;
  const float* v0 = vb + (size_t)chunk * CHUNK * 64 + y;
  const float* v1 = v0 + 32;
  const float* bp = betab + (size_t)chunk * CHUNK;
  float* o0 = ob + (size_t)chunk * CHUNK * 64 + y;
  float* o1 = o0 + 32;
  const float* sin0 = sinbuf + (size_t)chunk * 8192;
  float sa0 = sin0[(size_t)(2 * l) * 64 + y], sb0 = sin0[(size_t)(2 * l + 1) * 64 + y];
  float sa1 = sin0[(size_t)(2 * l) * 64 + y + 32], sb1 = sin0[(size_t)(2 * l + 1) * 64 + y + 32];
  float2 kv = k2[l], av = a2[l], qv = q2[l];
  float vt0 = v0[0], vt1 = v1[0], bt = bp[0];
  for (int t = 0; t < CHUNK; ++t) {
    int tn = (t + 1 < CHUNK) ? t + 1 : CHUNK - 1;
    float2 kn = k2[(size_t)tn * 64 + l];
    float2 an = a2[(size_t)tn * 64 + l];
    float2 qn = q2[(size_t)tn * 64 + l];
    float vn0 = v0[(size_t)tn * 64];
    float vn1 = v1[(size_t)tn * 64];
    float bn = bp[tn];
    sa0 *= av.x; sb0 *= av.y;
    sa1 *= av.x; sb1 *= av.y;
    float d0 = kv.x * sa0 + kv.y * sb0;
    float d1 = kv.x * sa1 + kv.y * sb1;
#pragma unroll
    for (int off = 1; off < 64; off <<= 1) {
      d0 += __shfl_xor(d0, off, 64);
      d1 += __shfl_xor(d1, off, 64);
    }
    float c0 = bt * (vt0 - d0);
    float c1 = bt * (vt1 - d1);
    sa0 = fmaf(c0, kv.x, sa0); sb0 = fmaf(c0, kv.y, sb0);
    sa1 = fmaf(c1, kv.x, sa1); sb1 = fmaf(c1, kv.y, sb1);
    float e0 = qv.x * sa0 + qv.y * sb0;
    float e1 = qv.x * sa1 + qv.y * sb1;
#pragma unroll
    for (int off = 1; off < 64; off <<= 1) {
      e0 += __shfl_xor(e0, off, 64);
      e1 += __shfl_xor(e1, off, 64);
    }
    if (l == 0) {
      o0[(size_t)t * 64] = e0;
      o1[(size_t)t * 64] = e1;
    }
    kv = kn; av = an; qv = qn; vt0 = vn0; vt1 = vn1; bt = bn;
  }
}

// ---------------- post: og16 = bf16(rmsnorm(o)*pnw*sigmoid(gate_pre)) ----------------
__global__ __launch_bounds__(256) void post_kernel(const float* __restrict__ ob,
                                                   const float* __restrict__ C1,
                                                   const float* __restrict__ pnw,
                                                   unsigned short* __restrict__ og16) {
  int row = blockIdx.x * 4 + (threadIdx.x >> 6);
  int c = threadIdx.x & 63;
  float o = ob[(size_t)row * DV + c];
  float ss = wave_sum(o * o);
  float scale = 1.0f / sqrtf(ss * (1.0f / DV) + RMS_EPS);
  float g = sigmoidf_(C1[(size_t)row * C1LD + 321 + c]);
  og16[(size_t)row * DV + c] = f2bf(o * scale * pnw[c] * g);
}

// ---------------- rmsnorm over d=1024 rows -> bf16 ----------------
__global__ __launch_bounds__(256) void rmsnorm_rows(const float* __restrict__ x,
                                                    const float* __restrict__ w,
                                                    unsigned short* __restrict__ y) {
  int row = blockIdx.x;
  const float4* x4 = (const float4*)(x + (size_t)row * D_MODEL);
  const float4* w4 = (const float4*)w;
  float4 v = x4[threadIdx.x];
  float ss = v.x * v.x + v.y * v.y + v.z * v.z + v.w * v.w;
  ss = wave_sum(ss);
  __shared__ float red[4];
  if ((threadIdx.x & 63) == 0) red[threadIdx.x >> 6] = ss;
  __syncthreads();
  float tot = red[0] + red[1] + red[2] + red[3];
  float scale = 1.0f / sqrtf(tot * (1.0f / D_MODEL) + RMS_EPS);
  float4 wv = w4[threadIdx.x];
  uint2 o;
  o.x = (unsigned)f2bf(v.x * scale * wv.x) | ((unsigned)f2bf(v.y * scale * wv.y) << 16);
  o.y = (unsigned)f2bf(v.z * scale * wv.z) | ((unsigned)f2bf(v.w * scale * wv.w) << 16);
  ((uint2*)(y + (size_t)row * D_MODEL))[threadIdx.x] = o;
}

// ---------------- GU16 = bf16(G * U) ----------------
__global__ void mul_to_bf16(const float* __restrict__ G, const float* __restrict__ U,
                            unsigned short* __restrict__ O, int n4) {
  int i = blockIdx.x * 256 + threadIdx.x;
  if (i >= n4) return;
  float4 g = ((const float4*)G)[i];
  float4 u = ((const float4*)U)[i];
  uint2 o;
  o.x = (unsigned)f2bf(g.x * u.x) | ((unsigned)f2bf(g.y * u.y) << 16);
  o.y = (unsigned)f2bf(g.z * u.z) | ((unsigned)f2bf(g.w * u.w) << 16);
  ((uint2*)O)[i] = o;
}

extern "C" void kernel_launch(void* const* d_in, const int* in_sizes, int n_in,
                              void* d_out, int out_size, void* d_ws, size_t ws_size,
                              hipStream_t stream) {
  const float* x_seq = (const float*)d_in[0];
  const float* W_q = (const float*)d_in[1];
  const float* W_k = (const float*)d_in[2];
  const float* W_v = (const float*)d_in[3];
  const float* pope_delta = (const float*)d_in[4];
  const float* W_a1 = (const float*)d_in[5];
  const float* W_a2 = (const float*)d_in[6];
  const float* W_beta = (const float*)d_in[7];
  const float* pnw = (const float*)d_in[8];
  const float* out_gate_W = (const float*)d_in[9];
  const float* W_out = (const float*)d_in[10];
  const float* ffn_norm_w = (const float*)d_in[11];
  const float* Wg = (const float*)d_in[12];
  const float* Wu = (const float*)d_in[13];
  const float* Wd = (const float*)d_in[14];
  float* out = (float*)d_out;

  float* F = (float*)d_ws;
  float* freq_f = F;                      // 64
  float* shift_f = F + 64;                // 64
  size_t o = 256;
  unsigned short* Wcat16 = (unsigned short*)(F + o); o += 262144;   // 512x1024 bf16
  unsigned short* Wg16   = (unsigned short*)(F + o); o += 524288;   // 1024x1024 bf16
  unsigned short* Wu16   = (unsigned short*)(F + o); o += 524288;
  unsigned short* Wd16   = (unsigned short*)(F + o); o += 524288;
  unsigned short* Wout16 = (unsigned short*)(F + o); o += 32768;    // 1024x64 bf16
  unsigned short* og16   = (unsigned short*)(F + o); o += 262144;   // 8192x64 bf16
  float* BIG = F + o;
  // phase 1 layout (within BIG)
  float* C1 = BIG;                        // 8192x512 f32
  float* qb = C1 + 4194304;               // 8192x128
  float* kb = qb + 1048576;
  float* alphab = kb + 1048576;
  float* a1s = alphab + 1048576;
  float* vb = a1s + 1048576;              // 8192x64
  float* betab = vb + 524288;             // 8192
  float* ob = betab + 8192;               // 8192x64
  float* PT = ob + 524288;                // 64x128x128
  float* fstate = PT + 1048576;           // 64x128x64
  float* sinbuf = fstate + 524288;        // 64x128x64
  unsigned short* x16 = (unsigned short*)(sinbuf + 524288);  // 8192x1024 bf16
  // phase 2 layout (reuses BIG; phase-1 buffers dead by then)
  unsigned short* hb16 = (unsigned short*)BIG;   // 8192x1024 bf16
  unsigned short* GU16 = (unsigned short*)BIG;   // aliases hb16 (dead after Wu GEMM)
  float* Gb = BIG + 4194304;              // 8192x1024 f32
  float* Ub = Gb + 8388608;               // 8192x1024 f32

  (void)in_sizes; (void)n_in; (void)out_size; (void)ws_size;

  init_tables<<<1, 64, 0, stream>>>(pope_delta, freq_f, shift_f);
  build_wcat16<<<(512 * 1024 + 255) / 256, 256, 0, stream>>>(W_q, W_k, W_v, W_a1, W_beta,
                                                             out_gate_W, Wcat16);
  conv_bf16<<<(2097152 + 255) / 256, 256, 0, stream>>>(x_seq, x16, 2097152);
  conv_weights<<<(802816 + 255) / 256, 256, 0, stream>>>(Wg, Wu, Wd, W_out,
                                                         Wg16, Wu16, Wd16, Wout16);
  // fused projection: C1 = x16 @ Wcat16^T  (8192 x 512, K=1024)
  gemm_bf16<<<dim3(64, 4), 256, 0, stream>>>(x16, Wcat16, nullptr, C1, T_SEQ, 512, 1024, 0);
  act_split<<<(T_SEQ * 193 + 255) / 256, 256, 0, stream>>>(C1, vb, a1s, betab);
  gemm_f32<<<dim3(128, 2), 256, 0, stream>>>(a1s, W_a2, nullptr, alphab, T_SEQ, DKP, DKP, 1);
  pope_kernel<<<(T_SEQ * DK + 255) / 256, 256, 0, stream>>>(C1, freq_f, shift_f, qb, kb);
  // chunked scan
  scan_passA<<<dim3(NCHUNK, 64), 64, 0, stream>>>(kb, alphab, vb, betab, PT, fstate);
  scan_combine<<<64, 256, 0, stream>>>(PT, fstate, sinbuf);
  scan_passB<<<dim3(NCHUNK, 32), 64, 0, stream>>>(qb, kb, alphab, vb, betab, sinbuf, ob);
  post_kernel<<<T_SEQ / 4, 256, 0, stream>>>(ob, C1, pnw, og16);
  // xres = x_seq + og @ W_out^T  (8192 x 1024, K=64) -> d_out
  gemm_bf16<<<dim3(64, 8), 256, 0, stream>>>(og16, Wout16, x_seq, out, T_SEQ, D_MODEL, 64, 0);
  rmsnorm_rows<<<T_SEQ, 256, 0, stream>>>(out, ffn_norm_w, hb16);
  // FFN
  gemm_bf16<<<dim3(64, 8), 256, 0, stream>>>(hb16, Wg16, nullptr, Gb, T_SEQ, D_MODEL, D_MODEL, 2);
  gemm_bf16<<<dim3(64, 8), 256, 0, stream>>>(hb16, Wu16, nullptr, Ub, T_SEQ, D_MODEL, D_MODEL, 0);
  mul_to_bf16<<<(2097152 + 255) / 256, 256, 0, stream>>>(Gb, Ub, GU16, 2097152);
  gemm_bf16<<<dim3(64, 8), 256, 0, stream>>>(GU16, Wd16, out, out, T_SEQ, D_MODEL, D_MODEL, 0);
}

// Round 7
// 535.762 us; speedup vs baseline: 11.6474x; 1.1665x over previous
//
#include <hip/hip_runtime.h>
#include <math.h>

#define T_SEQ 8192
#define D_MODEL 1024
#define DK 64
#define DKP 128
#define DV 64
#define C1LD 512   // padded fused-projection width (385 -> 512)
#define RMS_EPS 1.1920929e-07f
#define CHUNK 128
#define NCHUNK 64  // T_SEQ / CHUNK

typedef __attribute__((ext_vector_type(8))) __bf16 bf16x8;
typedef __attribute__((ext_vector_type(4))) float f32x4;

__device__ __forceinline__ float wave_sum(float x) {
#pragma unroll
  for (int off = 1; off < 64; off <<= 1) x += __shfl_xor(x, off, 64);
  return x;
}

// DPP row_ror rotate-reduce within 16-lane groups: VALU-pipe only, no LDS traffic.
template <int CTRL>
__device__ __forceinline__ float dpp_add(float x) {
  return x + __int_as_float(
                 __builtin_amdgcn_update_dpp(0, __float_as_int(x), CTRL, 0xF, 0xF, false));
}
__device__ __forceinline__ float sum16(float x) {
  x = dpp_add<0x121>(x);  // row_ror:1
  x = dpp_add<0x122>(x);  // row_ror:2
  x = dpp_add<0x124>(x);  // row_ror:4
  x = dpp_add<0x128>(x);  // row_ror:8
  return x;               // every lane holds the 16-lane sum
}

__device__ __forceinline__ float sigmoidf_(float x) { return 1.0f / (1.0f + expf(-x)); }
__device__ __forceinline__ float siluf_(float x) { return x / (1.0f + expf(-x)); }

__device__ __forceinline__ unsigned short f2bf(float f) {
  unsigned u = __float_as_uint(f);
  u += 0x7fff + ((u >> 16) & 1);  // RNE
  return (unsigned short)(u >> 16);
}

// ---------------- tables: f32 freq and f32 k-phase shift (match numpy f32 semantics) ------
__global__ void init_tables(const float* __restrict__ delta, float* __restrict__ freq,
                            float* __restrict__ shift) {
  int i = threadIdx.x;  // 64
  freq[i] = (float)pow(10000.0, (double)i / 64.0);
  float s = 1.0f / (1.0f + expf(-delta[i]));
  shift[i] = -6.2831855f * s;
}

// ---------------- concat weights (bf16, padded to 512 rows) ----------------
__global__ void build_wcat16(const float* __restrict__ Wq, const float* __restrict__ Wk,
                             const float* __restrict__ Wv, const float* __restrict__ Wa1,
                             const float* __restrict__ Wb, const float* __restrict__ Wg,
                             unsigned short* __restrict__ W16) {
  int idx = blockIdx.x * 256 + threadIdx.x;
  if (idx >= 512 * 1024) return;
  int row = idx >> 10, col = idx & 1023;
  float v = 0.f;
  if (row < 64) v = Wq[row * 1024 + col];
  else if (row < 128) v = Wk[(row - 64) * 1024 + col];
  else if (row < 192) v = Wv[(row - 128) * 1024 + col];
  else if (row < 320) v = Wa1[(row - 192) * 1024 + col];
  else if (row == 320) v = Wb[col];
  else if (row < 385) v = Wg[(row - 321) * 1024 + col];
  W16[idx] = f2bf(v);
}

// ---------------- f32 -> bf16 convert (float4 -> 4x bf16) ----------------
__global__ void conv_bf16(const float* __restrict__ in, unsigned short* __restrict__ out,
                          int n4) {
  int i = blockIdx.x * 256 + threadIdx.x;
  if (i >= n4) return;
  float4 v = ((const float4*)in)[i];
  uint2 o;
  o.x = (unsigned)f2bf(v.x) | ((unsigned)f2bf(v.y) << 16);
  o.y = (unsigned)f2bf(v.z) | ((unsigned)f2bf(v.w) << 16);
  ((uint2*)out)[i] = o;
}

// ---------------- fused weight conversions (Wg, Wu, Wd, W_out) ----------------
__global__ void conv_weights(const float* __restrict__ Wg, const float* __restrict__ Wu,
                             const float* __restrict__ Wd, const float* __restrict__ Wo,
                             unsigned short* __restrict__ Wg16, unsigned short* __restrict__ Wu16,
                             unsigned short* __restrict__ Wd16, unsigned short* __restrict__ Wo16) {
  int i = blockIdx.x * 256 + threadIdx.x;  // float4 groups
  const float* src;
  unsigned short* dst;
  int base;
  if (i < 262144) { src = Wg; dst = Wg16; base = i; }
  else if (i < 524288) { src = Wu; dst = Wu16; base = i - 262144; }
  else if (i < 786432) { src = Wd; dst = Wd16; base = i - 524288; }
  else if (i < 802816) { src = Wo; dst = Wo16; base = i - 786432; }
  else return;
  float4 v = ((const float4*)src)[base];
  uint2 o;
  o.x = (unsigned)f2bf(v.x) | ((unsigned)f2bf(v.y) << 16);
  o.y = (unsigned)f2bf(v.z) | ((unsigned)f2bf(v.w) << 16);
  ((uint2*)dst)[base] = o;
}

// ---------------- bf16 MFMA GEMM (m97 structure): C(f32) = act(A @ B^T [+ add]) ----------
__global__ __launch_bounds__(256) void gemm_bf16(const unsigned short* __restrict__ A,
                                                 const unsigned short* __restrict__ B,
                                                 const float* __restrict__ add,
                                                 float* __restrict__ C,
                                                 int M, int N, int K, int act) {
  __shared__ unsigned short As[128 * 32];
  __shared__ unsigned short Bs[128 * 32];
  const int tid = threadIdx.x;
  const int tm0 = blockIdx.x * 128, tn0 = blockIdx.y * 128;
  const int lane = tid & 63;
  const int w = tid >> 6;
  const int wr = (w >> 1) * 64, wc = (w & 1) * 64;
  const int fr = lane & 15, fq = lane >> 4;
  const int seg = w << 5;              // wave's 32-row segment of the tile
  const int srow = lane >> 2;          // 0..15 within a 16-row staging call
  const int skc = (lane & 3) * 8;      // k element offset (8 bf16 = 16 B)
  f32x4 acc[4][4];
#pragma unroll
  for (int a = 0; a < 4; ++a)
#pragma unroll
    for (int b = 0; b < 4; ++b) acc[a][b] = (f32x4){0.f, 0.f, 0.f, 0.f};

  for (int k0 = 0; k0 < K; k0 += 32) {
    __syncthreads();
#pragma unroll
    for (int j = 0; j < 2; ++j) {
      int r = seg + j * 16 + srow;
      __builtin_amdgcn_global_load_lds(
          (const __attribute__((address_space(1))) unsigned int*)(A + (size_t)(tm0 + r) * K + k0 + skc),
          (__attribute__((address_space(3))) unsigned int*)(As + (seg + j * 16) * 32),
          16, 0, 0);
      __builtin_amdgcn_global_load_lds(
          (const __attribute__((address_space(1))) unsigned int*)(B + (size_t)(tn0 + r) * K + k0 + skc),
          (__attribute__((address_space(3))) unsigned int*)(Bs + (seg + j * 16) * 32),
          16, 0, 0);
    }
    __syncthreads();
    bf16x8 af[4], bfr[4];
#pragma unroll
    for (int a = 0; a < 4; ++a)
      af[a] = *(const bf16x8*)(As + (wr + a * 16 + fr) * 32 + fq * 8);
#pragma unroll
    for (int b = 0; b < 4; ++b)
      bfr[b] = *(const bf16x8*)(Bs + (wc + b * 16 + fr) * 32 + fq * 8);
#pragma unroll
    for (int a = 0; a < 4; ++a)
#pragma unroll
      for (int b = 0; b < 4; ++b)
        acc[a][b] = __builtin_amdgcn_mfma_f32_16x16x32_bf16(af[a], bfr[b], acc[a][b], 0, 0, 0);
  }
#pragma unroll
  for (int a = 0; a < 4; ++a) {
#pragma unroll
    for (int b = 0; b < 4; ++b) {
#pragma unroll
      for (int r = 0; r < 4; ++r) {
        int row = tm0 + wr + a * 16 + fq * 4 + r;
        int col = tn0 + wc + b * 16 + fr;
        float v = acc[a][b][r];
        if (add) v += add[(size_t)row * N + col];
        if (act == 2) v = v / (1.0f + expf(-v));
        C[(size_t)row * N + col] = v;
      }
    }
  }
}

// ---------------- generic f32 GEMM (kept for the small alpha2 GEMM) ----------------
__global__ __launch_bounds__(256) void gemm_f32(const float* __restrict__ A,
                                                const float* __restrict__ B,
                                                const float* __restrict__ add,
                                                float* __restrict__ C,
                                                int M, int N, int K, int act) {
  __shared__ float As[16][68];
  __shared__ float Bs[16][68];
  const int bm = blockIdx.x * 64;
  const int bn = blockIdx.y * 64;
  const int tid = threadIdx.x;
  const int tm = tid >> 4, tn = tid & 15;
  const int lk = (tid & 3) << 2, lm = tid >> 2;
  float acc[4][4] = {{0.f}};
  const int ar = bm + lm;
  const int br = bn + lm;
  for (int k0 = 0; k0 < K; k0 += 16) {
    float4 a4 = make_float4(0.f, 0.f, 0.f, 0.f);
    float4 b4 = make_float4(0.f, 0.f, 0.f, 0.f);
    if (ar < M) a4 = *(const float4*)(A + (size_t)ar * K + k0 + lk);
    if (br < N) b4 = *(const float4*)(B + (size_t)br * K + k0 + lk);
    __syncthreads();
    As[lk][lm] = a4.x; As[lk + 1][lm] = a4.y; As[lk + 2][lm] = a4.z; As[lk + 3][lm] = a4.w;
    Bs[lk][lm] = b4.x; Bs[lk + 1][lm] = b4.y; Bs[lk + 2][lm] = b4.z; Bs[lk + 3][lm] = b4.w;
    __syncthreads();
#pragma unroll
    for (int kk = 0; kk < 16; ++kk) {
      float4 av = *(const float4*)&As[kk][tm << 2];
      float4 bv = *(const float4*)&Bs[kk][tn << 2];
      float a_[4] = {av.x, av.y, av.z, av.w};
      float b_[4] = {bv.x, bv.y, bv.z, bv.w};
#pragma unroll
      for (int i = 0; i < 4; ++i)
#pragma unroll
        for (int j = 0; j < 4; ++j) acc[i][j] = fmaf(a_[i], b_[j], acc[i][j]);
    }
  }
#pragma unroll
  for (int i = 0; i < 4; ++i) {
    int row = bm + (tm << 2) + i;
    if (row >= M) continue;
#pragma unroll
    for (int j = 0; j < 4; ++j) {
      int col = bn + (tn << 2) + j;
      if (col >= N) continue;
      float r = acc[i][j];
      if (add) r += add[(size_t)row * N + col];
      if (act == 1) r = 1.0f / (1.0f + expf(-r));
      else if (act == 2) r = r / (1.0f + expf(-r));
      C[(size_t)row * N + col] = r;
    }
  }
}

// ---------------- activations: v=silu, a1=silu, beta=sigmoid ----------------
__global__ void act_split(const float* __restrict__ C1, float* __restrict__ vb,
                          float* __restrict__ a1s, float* __restrict__ betab) {
  int idx = blockIdx.x * 256 + threadIdx.x;
  if (idx >= T_SEQ * 193) return;
  int t = idx / 193, j = idx % 193;
  if (j < 64) {
    float x = C1[(size_t)t * C1LD + 128 + j];
    vb[(size_t)t * DV + j] = siluf_(x);
  } else if (j < 192) {
    float x = C1[(size_t)t * C1LD + 192 + (j - 64)];
    a1s[(size_t)t * DKP + (j - 64)] = siluf_(x);
  } else {
    betab[t] = sigmoidf_(C1[(size_t)t * C1LD + 320]);
  }
}

// ---------------- PoPE: f32 phase arithmetic (matches numpy), accurate trig ----------------
__global__ __launch_bounds__(256) void pope_kernel(const float* __restrict__ C1,
                                                   const float* __restrict__ freq,
                                                   const float* __restrict__ shift,
                                                   float* __restrict__ qb, float* __restrict__ kb) {
  int idx = blockIdx.x * 256 + threadIdx.x;
  if (idx >= T_SEQ * DK) return;
  int t = idx >> 6;
  int i = idx & 63;
  const double TWO_PI = 6.283185307179586476925286766559;
  const double INV_TWO_PI = 0.15915494309189533576888376337251;
  float phiq = (float)t * freq[i];          // f32 multiply (matches numpy)
  float phik = phiq + shift[i];             // f32 add (matches numpy)
  float xq = C1[(size_t)t * C1LD + i];
  float muq = xq > 15.f ? xq : log1pf(expf(xq));
  double w = (double)phiq * INV_TWO_PI;
  w -= floor(w);
  float aq = (float)(w * TWO_PI);
  qb[(size_t)t * DKP + i] = muq * cosf(aq);
  qb[(size_t)t * DKP + 64 + i] = muq * sinf(aq);
  float xk = C1[(size_t)t * C1LD + DK + i];
  float muk = xk > 15.f ? xk : log1pf(expf(xk));
  double wk = (double)phik * INV_TWO_PI;
  wk -= floor(wk);
  float ak = (float)(wk * TWO_PI);
  kb[(size_t)t * DKP + i] = muk * cosf(ak);
  kb[(size_t)t * DKP + 64 + i] = muk * sinf(ak);
}

// ================= chunked scan (DPP rotate-reduce, no LDS-pipe traffic) =================
// Layout: 16 lanes per column, 8 k-dims per lane (sub-lane sl = l&15 owns dims sl*8..sl*8+7),
// 4 columns per wave (subgroup g = l>>4). The 128-dim dot = 8 in-lane FMAs + sum16 (DPP).

// Pass A: tasks 0..127 basis columns (waves 0..31), 128..191 driven columns (waves 32..47).
__global__ __launch_bounds__(64) void scan_passA(const float* __restrict__ kb,
                                                 const float* __restrict__ alphab,
                                                 const float* __restrict__ vb,
                                                 const float* __restrict__ betab,
                                                 float* __restrict__ PT,
                                                 float* __restrict__ fstate) {
  const int chunk = blockIdx.x;
  const int w = blockIdx.y;            // 0..47
  const int l = threadIdx.x;
  const int sl = l & 15;
  const int task = w * 4 + (l >> 4);   // 0..191; isP is wave-uniform (128 % 4 == 0)
  const bool isP = (task < 128);
  const int c = isP ? 0 : (task - 128);
  const float* kc = kb + (size_t)chunk * CHUNK * DKP + sl * 8;
  const float* ac = alphab + (size_t)chunk * CHUNK * DKP + sl * 8;
  const float* vcol = vb + (size_t)chunk * CHUNK * DV + c;
  const float* bp = betab + (size_t)chunk * CHUNK;
  float s[8];
#pragma unroll
  for (int i = 0; i < 8; ++i) s[i] = (isP && (sl * 8 + i == task)) ? 1.f : 0.f;
  float4 k0 = *(const float4*)kc, k1 = *(const float4*)(kc + 4);
  float4 a0 = *(const float4*)ac, a1 = *(const float4*)(ac + 4);
  float vt = isP ? 0.f : vcol[0];
  float bt = bp[0];
  for (int t = 0; t < CHUNK; ++t) {
    const int tn = (t + 1 < CHUNK) ? t + 1 : CHUNK - 1;
    float4 nk0 = *(const float4*)(kc + (size_t)tn * DKP);
    float4 nk1 = *(const float4*)(kc + (size_t)tn * DKP + 4);
    float4 na0 = *(const float4*)(ac + (size_t)tn * DKP);
    float4 na1 = *(const float4*)(ac + (size_t)tn * DKP + 4);
    float nv = isP ? 0.f : vcol[(size_t)tn * DV];
    float nb = bp[tn];
    s[0] *= a0.x; s[1] *= a0.y; s[2] *= a0.z; s[3] *= a0.w;
    s[4] *= a1.x; s[5] *= a1.y; s[6] *= a1.z; s[7] *= a1.w;
    float e0 = fmaf(s[1], k0.y, s[0] * k0.x);
    float e1 = fmaf(s[3], k0.w, s[2] * k0.z);
    float e2 = fmaf(s[5], k1.y, s[4] * k1.x);
    float e3 = fmaf(s[7], k1.w, s[6] * k1.z);
    float d = sum16((e0 + e1) + (e2 + e3));
    float cf = bt * (vt - d);
    s[0] = fmaf(cf, k0.x, s[0]); s[1] = fmaf(cf, k0.y, s[1]);
    s[2] = fmaf(cf, k0.z, s[2]); s[3] = fmaf(cf, k0.w, s[3]);
    s[4] = fmaf(cf, k1.x, s[4]); s[5] = fmaf(cf, k1.y, s[5]);
    s[6] = fmaf(cf, k1.z, s[6]); s[7] = fmaf(cf, k1.w, s[7]);
    k0 = nk0; k1 = nk1; a0 = na0; a1 = na1; vt = nv; bt = nb;
  }
  if (isP) {
    float* dst = PT + (size_t)chunk * 16384 + (size_t)task * 128 + sl * 8;
    *(float4*)dst = make_float4(s[0], s[1], s[2], s[3]);
    *(float4*)(dst + 4) = make_float4(s[4], s[5], s[6], s[7]);
  } else {
#pragma unroll
    for (int i = 0; i < 8; ++i)
      fstate[(size_t)chunk * 8192 + (size_t)(sl * 8 + i) * 64 + c] = s[i];
  }
}

// Combine: per column c, sequentially s_in(j+1) = P_j s_in(j) + f_j.
// 2 K-halves x 128 rows; P_j register-double-buffered one iteration ahead.
__global__ __launch_bounds__(256) void scan_combine(const float* __restrict__ PT,
                                                    const float* __restrict__ fstate,
                                                    float* __restrict__ sinbuf) {
  const int c = blockIdx.x;            // 0..63
  const int r = threadIdx.x & 127;     // row
  const int h = threadIdx.x >> 7;      // K-half
  __shared__ float sv[128];
  __shared__ float part[128];
  float bufA[64], bufB[64];
  const float* Pbase = PT + (size_t)h * 64 * 128 + r;
#pragma unroll
  for (int jj = 0; jj < 64; ++jj) bufA[jj] = Pbase[(size_t)jj * 128];
  float s = 0.f;
#define COMBINE_ITER(J, CUR, NXT)                                                  \
  {                                                                                \
    if (h == 0) {                                                                  \
      sinbuf[(size_t)(J) * 8192 + (size_t)r * 64 + c] = s;                         \
      sv[r] = s;                                                                   \
    }                                                                              \
    __syncthreads();                                                               \
    int jn = ((J) + 1 < NCHUNK) ? (J) + 1 : NCHUNK - 1;                            \
    const float* Pn = Pbase + (size_t)jn * 16384;                                  \
    _Pragma("unroll")                                                              \
    for (int jj = 0; jj < 64; ++jj) NXT[jj] = Pn[(size_t)jj * 128];                \
    const float* svh = sv + h * 64;                                                \
    float a0 = (h == 0) ? fstate[(size_t)(J) * 8192 + (size_t)r * 64 + c] : 0.f;   \
    float a1 = 0.f, a2 = 0.f, a3 = 0.f;                                            \
    _Pragma("unroll")                                                              \
    for (int jj = 0; jj < 64; jj += 4) {                                           \
      a0 = fmaf(CUR[jj], svh[jj], a0);                                             \
      a1 = fmaf(CUR[jj + 1], svh[jj + 1], a1);                                     \
      a2 = fmaf(CUR[jj + 2], svh[jj + 2], a2);                                     \
      a3 = fmaf(CUR[jj + 3], svh[jj + 3], a3);                                     \
    }                                                                              \
    float tot = (a0 + a1) + (a2 + a3);                                             \
    if (h == 1) part[r] = tot;                                                     \
    __syncthreads();                                                               \
    if (h == 0) s = tot + part[r];                                                 \
  }
  for (int j = 0; j < NCHUNK; j += 2) {
    COMBINE_ITER(j, bufA, bufB)
    COMBINE_ITER(j + 1, bufB, bufA)
  }
#undef COMBINE_ITER
}

// Pass B: 4 columns/wave (c = blockIdx.y*4 + g), exact per-column scan, emits outputs.
__global__ __launch_bounds__(64) void scan_passB(const float* __restrict__ qb,
                                                 const float* __restrict__ kb,
                                                 const float* __restrict__ alphab,
                                                 const float* __restrict__ vb,
                                                 const float* __restrict__ betab,
                                                 const float* __restrict__ sinbuf,
                                                 float* __restrict__ ob) {
  const int chunk = blockIdx.x;
  const int l = threadIdx.x;
  const int sl = l & 15;
  const int c = blockIdx.y * 4 + (l >> 4);  // 0..63
  const float* kc = kb + (size_t)chunk * CHUNK * DKP + sl * 8;
  const float* ac = alphab + (size_t)chunk * CHUNK * DKP + sl * 8;
  const float* qc = qb + (size_t)chunk * CHUNK * DKP + sl * 8;
  const float* vcol = vb + (size_t)chunk * CHUNK * DV + c;
  const float* bp = betab + (size_t)chunk * CHUNK;
  float* ocol = ob + (size_t)chunk * CHUNK * DV + c;
  float s[8];
#pragma unroll
  for (int i = 0; i < 8; ++i)
    s[i] = sinbuf[(size_t)chunk * 8192 + (size_t)(sl * 8 + i) * 64 + c];
  float4 k0 = *(const float4*)kc, k1 = *(const float4*)(kc + 4);
  float4 a0 = *(const float4*)ac, a1 = *(const float4*)(ac + 4);
  float4 q0 = *(const float4*)qc, q1 = *(const float4*)(qc + 4);
  float vt = vcol[0], bt = bp[0];
  for (int t = 0; t < CHUNK; ++t) {
    const int tn = (t + 1 < CHUNK) ? t + 1 : CHUNK - 1;
    float4 nk0 = *(const float4*)(kc + (size_t)tn * DKP);
    float4 nk1 = *(const float4*)(kc + (size_t)tn * DKP + 4);
    float4 na0 = *(const float4*)(ac + (size_t)tn * DKP);
    float4 na1 = *(const float4*)(ac + (size_t)tn * DKP + 4);
    float4 nq0 = *(const float4*)(qc + (size_t)tn * DKP);
    float4 nq1 = *(const float4*)(qc + (size_t)tn * DKP + 4);
    float nv = vcol[(size_t)tn * DV];
    float nb = bp[tn];
    s[0] *= a0.x; s[1] *= a0.y; s[2] *= a0.z; s[3] *= a0.w;
    s[4] *= a1.x; s[5] *= a1.y; s[6] *= a1.z; s[7] *= a1.w;
    float e0 = fmaf(s[1], k0.y, s[0] * k0.x);
    float e1 = fmaf(s[3], k0.w, s[2] * k0.z);
    float e2 = fmaf(s[5], k1.y, s[4] * k1.x);
    float e3 = fmaf(s[7], k1.w, s[6] * k1.z);
    float d = sum16((e0 + e1) + (e2 + e3));
    float cf = bt * (vt - d);
    s[0] = fmaf(cf, k0.x, s[0]); s[1] = fmaf(cf, k0.y, s[1]);
    s[2] = fmaf(cf, k0.z, s[2]); s[3] = fmaf(cf, k0.w, s[3]);
    s[4] = fmaf(cf, k1.x, s[4]); s[5] = fmaf(cf, k1.y, s[5]);
    s[6] = fmaf(cf, k1.z, s[6]); s[7] = fmaf(cf, k1.w, s[7]);
    float f0 = fmaf(s[1], q0.y, s[0] * q0.x);
    float f1 = fmaf(s[3], q0.w, s[2] * q0.z);
    float f2 = fmaf(s[5], q1.y, s[4] * q1.x);
    float f3 = fmaf(s[7], q1.w, s[6] * q1.z);
    float e = sum16((f0 + f1) + (f2 + f3));
    if (sl == 0) ocol[(size_t)t * DV] = e;
    k0 = nk0; k1 = nk1; a0 = na0; a1 = na1; q0 = nq0; q1 = nq1; vt = nv; bt = nb;
  }
}

// ---------------- post: og16 = bf16(rmsnorm(o)*pnw*sigmoid(gate_pre)) ----------------
__global__ __launch_bounds__(256) void post_kernel(const float* __restrict__ ob,
                                                   const float* __restrict__ C1,
                                                   const float* __restrict__ pnw,
                                                   unsigned short* __restrict__ og16) {
  int row = blockIdx.x * 4 + (threadIdx.x >> 6);
  int c = threadIdx.x & 63;
  float o = ob[(size_t)row * DV + c];
  float ss = wave_sum(o * o);
  float scale = 1.0f / sqrtf(ss * (1.0f / DV) + RMS_EPS);
  float g = sigmoidf_(C1[(size_t)row * C1LD + 321 + c]);
  og16[(size_t)row * DV + c] = f2bf(o * scale * pnw[c] * g);
}

// ---------------- rmsnorm over d=1024 rows -> bf16 ----------------
__global__ __launch_bounds__(256) void rmsnorm_rows(const float* __restrict__ x,
                                                    const float* __restrict__ w,
                                                    unsigned short* __restrict__ y) {
  int row = blockIdx.x;
  const float4* x4 = (const float4*)(x + (size_t)row * D_MODEL);
  const float4* w4 = (const float4*)w;
  float4 v = x4[threadIdx.x];
  float ss = v.x * v.x + v.y * v.y + v.z * v.z + v.w * v.w;
  ss = wave_sum(ss);
  __shared__ float red[4];
  if ((threadIdx.x & 63) == 0) red[threadIdx.x >> 6] = ss;
  __syncthreads();
  float tot = red[0] + red[1] + red[2] + red[3];
  float scale = 1.0f / sqrtf(tot * (1.0f / D_MODEL) + RMS_EPS);
  float4 wv = w4[threadIdx.x];
  uint2 o;
  o.x = (unsigned)f2bf(v.x * scale * wv.x) | ((unsigned)f2bf(v.y * scale * wv.y) << 16);
  o.y = (unsigned)f2bf(v.z * scale * wv.z) | ((unsigned)f2bf(v.w * scale * wv.w) << 16);
  ((uint2*)(y + (size_t)row * D_MODEL))[threadIdx.x] = o;
}

// ---------------- GU16 = bf16(G * U) ----------------
__global__ void mul_to_bf16(const float* __restrict__ G, const float* __restrict__ U,
                            unsigned short* __restrict__ O, int n4) {
  int i = blockIdx.x * 256 + threadIdx.x;
  if (i >= n4) return;
  float4 g = ((const float4*)G)[i];
  float4 u = ((const float4*)U)[i];
  uint2 o;
  o.x = (unsigned)f2bf(g.x * u.x) | ((unsigned)f2bf(g.y * u.y) << 16);
  o.y = (unsigned)f2bf(g.z * u.z) | ((unsigned)f2bf(g.w * u.w) << 16);
  ((uint2*)O)[i] = o;
}

extern "C" void kernel_launch(void* const* d_in, const int* in_sizes, int n_in,
                              void* d_out, int out_size, void* d_ws, size_t ws_size,
                              hipStream_t stream) {
  const float* x_seq = (const float*)d_in[0];
  const float* W_q = (const float*)d_in[1];
  const float* W_k = (const float*)d_in[2];
  const float* W_v = (const float*)d_in[3];
  const float* pope_delta = (const float*)d_in[4];
  const float* W_a1 = (const float*)d_in[5];
  const float* W_a2 = (const float*)d_in[6];
  const float* W_beta = (const float*)d_in[7];
  const float* pnw = (const float*)d_in[8];
  const float* out_gate_W = (const float*)d_in[9];
  const float* W_out = (const float*)d_in[10];
  const float* ffn_norm_w = (const float*)d_in[11];
  const float* Wg = (const float*)d_in[12];
  const float* Wu = (const float*)d_in[13];
  const float* Wd = (const float*)d_in[14];
  float* out = (float*)d_out;

  float* F = (float*)d_ws;
  float* freq_f = F;                      // 64
  float* shift_f = F + 64;                // 64
  size_t o = 256;
  unsigned short* Wcat16 = (unsigned short*)(F + o); o += 262144;   // 512x1024 bf16
  unsigned short* Wg16   = (unsigned short*)(F + o); o += 524288;   // 1024x1024 bf16
  unsigned short* Wu16   = (unsigned short*)(F + o); o += 524288;
  unsigned short* Wd16   = (unsigned short*)(F + o); o += 524288;
  unsigned short* Wout16 = (unsigned short*)(F + o); o += 32768;    // 1024x64 bf16
  unsigned short* og16   = (unsigned short*)(F + o); o += 262144;   // 8192x64 bf16
  float* BIG = F + o;
  // phase 1 layout (within BIG)
  float* C1 = BIG;                        // 8192x512 f32
  float* qb = C1 + 4194304;               // 8192x128
  float* kb = qb + 1048576;
  float* alphab = kb + 1048576;
  float* a1s = alphab + 1048576;
  float* vb = a1s + 1048576;              // 8192x64
  float* betab = vb + 524288;             // 8192
  float* ob = betab + 8192;               // 8192x64
  float* PT = ob + 524288;                // 64x128x128
  float* fstate = PT + 1048576;           // 64x128x64
  float* sinbuf = fstate + 524288;        // 64x128x64
  unsigned short* x16 = (unsigned short*)(sinbuf + 524288);  // 8192x1024 bf16
  // phase 2 layout (reuses BIG; phase-1 buffers dead by then)
  unsigned short* hb16 = (unsigned short*)BIG;   // 8192x1024 bf16
  unsigned short* GU16 = (unsigned short*)BIG;   // aliases hb16 (dead after Wu GEMM)
  float* Gb = BIG + 4194304;              // 8192x1024 f32
  float* Ub = Gb + 8388608;               // 8192x1024 f32

  (void)in_sizes; (void)n_in; (void)out_size; (void)ws_size;

  init_tables<<<1, 64, 0, stream>>>(pope_delta, freq_f, shift_f);
  build_wcat16<<<(512 * 1024 + 255) / 256, 256, 0, stream>>>(W_q, W_k, W_v, W_a1, W_beta,
                                                             out_gate_W, Wcat16);
  conv_bf16<<<(2097152 + 255) / 256, 256, 0, stream>>>(x_seq, x16, 2097152);
  conv_weights<<<(802816 + 255) / 256, 256, 0, stream>>>(Wg, Wu, Wd, W_out,
                                                         Wg16, Wu16, Wd16, Wout16);
  // fused projection: C1 = x16 @ Wcat16^T  (8192 x 512, K=1024)
  gemm_bf16<<<dim3(64, 4), 256, 0, stream>>>(x16, Wcat16, nullptr, C1, T_SEQ, 512, 1024, 0);
  act_split<<<(T_SEQ * 193 + 255) / 256, 256, 0, stream>>>(C1, vb, a1s, betab);
  gemm_f32<<<dim3(128, 2), 256, 0, stream>>>(a1s, W_a2, nullptr, alphab, T_SEQ, DKP, DKP, 1);
  pope_kernel<<<(T_SEQ * DK + 255) / 256, 256, 0, stream>>>(C1, freq_f, shift_f, qb, kb);
  // chunked scan
  scan_passA<<<dim3(NCHUNK, 48), 64, 0, stream>>>(kb, alphab, vb, betab, PT, fstate);
  scan_combine<<<64, 256, 0, stream>>>(PT, fstate, sinbuf);
  scan_passB<<<dim3(NCHUNK, 16), 64, 0, stream>>>(qb, kb, alphab, vb, betab, sinbuf, ob);
  post_kernel<<<T_SEQ / 4, 256, 0, stream>>>(ob, C1, pnw, og16);
  // xres = x_seq + og @ W_out^T  (8192 x 1024, K=64) -> d_out
  gemm_bf16<<<dim3(64, 8), 256, 0, stream>>>(og16, Wout16, x_seq, out, T_SEQ, D_MODEL, 64, 0);
  rmsnorm_rows<<<T_SEQ, 256, 0, stream>>>(out, ffn_norm_w, hb16);
  // FFN
  gemm_bf16<<<dim3(64, 8), 256, 0, stream>>>(hb16, Wg16, nullptr, Gb, T_SEQ, D_MODEL, D_MODEL, 2);
  gemm_bf16<<<dim3(64, 8), 256, 0, stream>>>(hb16, Wu16, nullptr, Ub, T_SEQ, D_MODEL, D_MODEL, 0);
  mul_to_bf16<<<(2097152 + 255) / 256, 256, 0, stream>>>(Gb, Ub, GU16, 2097152);
  gemm_bf16<<<dim3(64, 8), 256, 0, stream>>>(GU16, Wd16, out, out, T_SEQ, D_MODEL, D_MODEL, 0);
}